// Round 13
// baseline (475.718 us; speedup 1.0000x reference)
//
#include <hip/hip_runtime.h>

// ---------------------------------------------------------------------------
// Cosine-similarity MHA, round 13:
//  projn v5: uniform-select base pointers (no runtime-indexed arrays ->
//    no scratch), 2-deep register prefetch (full HBM latency hiding),
//    __launch_bounds__(512,8) -> 4 blocks/CU.
//  attn2: __launch_bounds__(512,8) -> 4 blocks/CU (LDS 39.9KB x4 fits).
//  rproj4 / wprep: unchanged.
// ---------------------------------------------------------------------------

#define NT 50
#define NC 200
#define EMB 128
#define DH 32
#define NH 8
#define THREADS 512
#define LOG2E 1.44269504088896340736f

#define WS_PROJ_LO 98304u       // short offset of proj lo plane
#define WS_R_HI    196608u      // short offset of R hi plane
#define WS_R_LO    229376u      // short offset of R lo plane
#define WS_PSW     262144u      // short offset of swizzled proj hi plane
#define WS_PLANES_B 720896u     // bytes: end of weight planes (incl swizzled)

typedef __attribute__((ext_vector_type(4))) float f4acc;
typedef __attribute__((ext_vector_type(8))) short bh8;

__device__ __forceinline__ f4acc mfma_bf16(bh8 a, bh8 b, f4acc c) {
    return __builtin_amdgcn_mfma_f32_16x16x32_bf16(a, b, c, 0, 0, 0);
}

__device__ __forceinline__ unsigned short bf16rne(float x) {
    unsigned int u = __float_as_uint(x);
    u += 0x7FFFu + ((u >> 16) & 1u);
    return (unsigned short)(u >> 16);
}

// 8 f32 -> bf16 RNE (packed); pair order identical for A and B operands.
__device__ __forceinline__ bh8 cvt8(const float* __restrict__ p) {
    float4 x0 = *reinterpret_cast<const float4*>(p);
    float4 x1 = *reinterpret_cast<const float4*>(p + 4);
    float xs[8] = {x0.x, x0.y, x0.z, x0.w, x1.x, x1.y, x1.z, x1.w};
    union { unsigned int w[4]; bh8 v; } H;
    #pragma unroll
    for (int i = 0; i < 4; ++i)
        asm("v_cvt_pk_bf16_f32 %0, %1, %2"
            : "=v"(H.w[i]) : "v"(xs[2 * i]), "v"(xs[2 * i + 1]));
    return H.v;
}

__device__ __forceinline__ void split8(const float* __restrict__ p, bh8& hi, bh8& lo) {
    float4 x0 = *reinterpret_cast<const float4*>(p);
    float4 x1 = *reinterpret_cast<const float4*>(p + 4);
    float xs[8] = {x0.x, x0.y, x0.z, x0.w, x1.x, x1.y, x1.z, x1.w};
    union { unsigned int w[4]; bh8 v; } H, L;
    #pragma unroll
    for (int i = 0; i < 4; ++i) {
        const float a = xs[2 * i], b = xs[2 * i + 1];
        unsigned int hw, lw;
        asm("v_cvt_pk_bf16_f32 %0, %1, %2" : "=v"(hw) : "v"(a), "v"(b));
        const float ha = __uint_as_float(hw << 16);
        const float hb = __uint_as_float(hw & 0xFFFF0000u);
        const float la = a - ha, lb = b - hb;
        asm("v_cvt_pk_bf16_f32 %0, %1, %2" : "=v"(lw) : "v"(la), "v"(lb));
        H.w[i] = hw; L.w[i] = lw;
    }
    hi = H.v; lo = L.v;
}

// ---- wprep: linear hi/lo planes + R planes + fragment-major swizzled plane --
__global__ __launch_bounds__(512) void wprep(
    const float* __restrict__ At_w, const float* __restrict__ Ac_w,
    const float* __restrict__ Bc_w, const float* __restrict__ R_w,
    unsigned short* __restrict__ ws)
{
    const int u = blockIdx.x * 512 + threadIdx.x;     // 28672 units of 8 elems
    bh8 h8, l8;
    if (u < 12288) {                                  // proj: [3][256][128]
        const int p = u >> 12, rem = u & 4095;
        const int col = rem >> 4, e0 = (rem & 15) << 3;
        const float* W = (p == 0) ? At_w : (p == 1) ? Ac_w : Bc_w;
        split8(W + (size_t)col * 128 + e0, h8, l8);
        const size_t o = ((size_t)p * 256 + col) * 128 + e0;
        *reinterpret_cast<bh8*>(ws + o) = h8;
        *reinterpret_cast<bh8*>(ws + WS_PROJ_LO + o) = l8;
    } else if (u < 16384) {                           // R: [128][256]
        const int u2 = u - 12288;
        const int e = u2 >> 5, k0 = (u2 & 31) << 3;
        split8(R_w + (size_t)e * 256 + k0, h8, l8);
        const size_t o = (size_t)e * 256 + k0;
        *reinterpret_cast<bh8*>(ws + WS_R_HI + o) = h8;
        *reinterpret_cast<bh8*>(ws + WS_R_LO + o) = l8;
    } else {                                          // swizzled proj hi
        const int u2 = u - 16384;                     // 12288 units
        const int lane = u2 & 63;
        const int ks = (u2 >> 6) & 3;
        const int colgrp = (u2 >> 8) & 1;
        const int head = (u2 >> 9) & 7;
        const int ty = u2 >> 12;
        const float* W = (ty == 0) ? At_w : (ty == 1) ? Ac_w : Bc_w;
        const int col = head * 32 + colgrp * 16 + (lane & 15);
        const int g = lane >> 4;
        *reinterpret_cast<bh8*>(ws + WS_PSW + (size_t)u2 * 8) =
            cvt8(W + (size_t)col * 128 + ks * 32 + g * 8);
    }
}

__device__ __forceinline__ void projn_wfrag(
    const unsigned short* __restrict__ wsp, int ty, int head, int lane,
    bh8* bf0, bh8* bf1)
{
    const unsigned short* base = wsp + WS_PSW + ((size_t)(ty * 8 + head) << 12)
                               + (size_t)lane * 8;
    #pragma unroll
    for (int ks = 0; ks < 4; ++ks) {
        bf0[ks] = *reinterpret_cast<const bh8*>(base + (ks << 9));
        bf1[ks] = *reinterpret_cast<const bh8*>(base + 2048 + (ks << 9));
    }
}

__device__ __forceinline__ void tinfo(int r, int& ty, int& mt, int& nrows) {
    ty = (r < 4) ? 0 : (r < 17) ? 1 : 2;
    mt = r - ((ty == 0) ? 0 : (ty == 1) ? 4 : 17);
    nrows = (ty == 0) ? NT : NC;
}

// ---- projn v5: persistent 10-tile pipelined block, 2-deep prefetch ----
// block = (batch, third): tiles r = third*10 .. third*10+9. Wave = head.
// No runtime-indexed pointer arrays (scratch hazard): uniform ternary selects.
__global__ __launch_bounds__(512, 8) void projn(
    const float* __restrict__ gq, const float* __restrict__ gk,
    const float* __restrict__ gv,
    const float* __restrict__ At_b, const float* __restrict__ Ac_b,
    const float* __restrict__ Bc_b,
    const unsigned short* __restrict__ wsp,
    unsigned short* __restrict__ qh, unsigned short* __restrict__ kh,
    unsigned short* __restrict__ vh)
{
    __shared__ __align__(16) float sX[2][16][132];
    __shared__ __align__(16) unsigned short sO[16 * 264];

    const int blk = blockIdx.x;
    const int b = blk / 3, third = blk - b * 3;
    const int t = threadIdx.x;
    const int lane = t & 63, head = t >> 6, l15 = lane & 15, g = lane >> 4;
    const int c0i = head * 32 + l15, c1i = c0i + 16;
    const int srow = t >> 5, scol = (t & 31) * 4;
    const int fr = lane >> 2, fc = lane & 3;

    // uniform base-pointer selects (s_cselect; no arrays -> no scratch)
    #define XBASE(TY) ((TY) == 0 ? gq + (size_t)b * NT * EMB \
                      : (TY) == 1 ? gk + (size_t)b * NC * EMB \
                                  : gv + (size_t)b * NC * EMB)
    #define OBASE(TY) ((TY) == 0 ? qh + (size_t)b * (NT * 256) \
                      : (TY) == 1 ? kh + (size_t)b * (NC * 256) \
                                  : vh + (size_t)b * (NC * 256))
    #define BBASE(TY) ((TY) == 0 ? At_b : (TY) == 1 ? Ac_b : Bc_b)

    const int r0 = third * 10;
    int ty, mt, nrows;
    tinfo(r0, ty, mt, nrows);

    // prologue: stage tile r0 -> sX[0]; W frags + bias for its type
    {
        int row = mt * 16 + srow; if (row > nrows - 1) row = nrows - 1;
        *reinterpret_cast<float4*>(&sX[0][srow][scol]) =
            *reinterpret_cast<const float4*>(XBASE(ty) + (size_t)row * EMB + scol);
    }
    bh8 bf0[4], bf1[4];
    projn_wfrag(wsp, ty, head, lane, bf0, bf1);
    float bias0 = BBASE(ty)[c0i], bias1 = BBASE(ty)[c1i];

    // prefetch tile r0+1 into xregA
    int tyA, mtA, nrA;
    tinfo(r0 + 1, tyA, mtA, nrA);
    float4 xregA;
    {
        int row = mtA * 16 + srow; if (row > nrA - 1) row = nrA - 1;
        xregA = *reinterpret_cast<const float4*>(
            XBASE(tyA) + (size_t)row * EMB + scol);
    }
    __syncthreads();

    for (int i = 0; i < 10; ++i) {
        const int cur = i & 1;
        const int cty = ty, cmt = mt, cnrows = nrows;

        // issue tile i+2 prefetch early (~2 tile-times to complete)
        float4 xregB;
        int tyB = tyA, mtB = mtA, nrB = nrA;
        if (i + 2 < 10) {
            tinfo(r0 + i + 2, tyB, mtB, nrB);
            int row = mtB * 16 + srow; if (row > nrB - 1) row = nrB - 1;
            xregB = *reinterpret_cast<const float4*>(
                XBASE(tyB) + (size_t)row * EMB + scol);
        }

        // compute current tile
        f4acc a0 = {bias0, bias0, bias0, bias0};
        f4acc a1 = {bias1, bias1, bias1, bias1};
        #pragma unroll
        for (int ks = 0; ks < 4; ++ks) {
            const bh8 xv = cvt8(&sX[cur][l15][ks * 32 + (g << 3)]);
            a0 = mfma_bf16(xv, bf0[ks], a0);
            a1 = mfma_bf16(xv, bf1[ks], a1);
        }
        if (cty < 2) {                                 // normalize q/k rows
            float s[4];
            #pragma unroll
            for (int rr = 0; rr < 4; ++rr) s[rr] = a0[rr] * a0[rr] + a1[rr] * a1[rr];
            #pragma unroll
            for (int rr = 0; rr < 4; ++rr) {
                s[rr] += __shfl_xor(s[rr], 1);
                s[rr] += __shfl_xor(s[rr], 2);
                s[rr] += __shfl_xor(s[rr], 4);
                s[rr] += __shfl_xor(s[rr], 8);
            }
            #pragma unroll
            for (int rr = 0; rr < 4; ++rr) {
                const float rs = rsqrtf(fmaxf(s[rr], 1e-12f));
                a0[rr] *= rs; a1[rr] *= rs;
            }
        }
        // pack into sO (wave-private columns head*32..head*32+31)
        #pragma unroll
        for (int rr = 0; rr < 4; ++rr) {
            const int row = (g << 2) + rr;
            sO[row * 264 + c0i] = bf16rne(a0[rr]);
            sO[row * 264 + c1i] = bf16rne(a1[rr]);
        }
        asm volatile("" ::: "memory");                 // pack before flush
        // wave-local flush (same wave wrote these 32 cols; DS in-order)
        {
            const int grow = cmt * 16 + fr;
            if (grow < cnrows)
                *reinterpret_cast<bh8*>(
                    OBASE(cty) + (size_t)grow * 256 + head * 32 + fc * 8) =
                    *reinterpret_cast<const bh8*>(&sO[fr * 264 + head * 32 + fc * 8]);
        }
        // rotate pipeline: write tile i+1 into other sX buffer
        if (i + 1 < 10) {
            *reinterpret_cast<float4*>(&sX[cur ^ 1][srow][scol]) = xregA;
            if (tyA != cty) {
                projn_wfrag(wsp, tyA, head, lane, bf0, bf1);
                bias0 = BBASE(tyA)[c0i]; bias1 = BBASE(tyA)[c1i];
            }
            ty = tyA; mt = mtA; nrows = nrA;
            tyA = tyB; mtA = mtB; nrA = nrB;
            xregA = xregB;
        }
        __syncthreads();
    }
    #undef XBASE
    #undef OBASE
    #undef BBASE
}

// ---- attn2: scores + softmax + att + PV + cat, from prestaged bf16 ----
__global__ __launch_bounds__(512, 8) void attn2(
    const unsigned short* __restrict__ qh, const unsigned short* __restrict__ kh,
    const unsigned short* __restrict__ vh, const float* __restrict__ pos_bias,
    float* __restrict__ att, float* __restrict__ cat, int nbat)
{
    const int t = threadIdx.x;
    const int p = blockIdx.x;
    const int chunk = (nbat * NH) >> 3;
    const int lj = (p & 7) * chunk + (p >> 3);
    const int b = lj >> 3, h = lj & 7;
    const int lane = t & 63, wave = t >> 6, l15 = lane & 15, g = lane >> 4;

    __shared__ __align__(16) unsigned char smem[39872];
    unsigned short* sVT = reinterpret_cast<unsigned short*>(smem);
    unsigned short* sK  = reinterpret_cast<unsigned short*>(smem + 14848);
    unsigned short* sQ  = reinterpret_cast<unsigned short*>(smem + 30848);
    unsigned short* sP  = reinterpret_cast<unsigned short*>(smem + 14848);
    float* spb = reinterpret_cast<float*>(smem + 38048);
    float* sSm = reinterpret_cast<float*>(smem + 39360);

    if (t < 448) {
        unsigned int* v32 = reinterpret_cast<unsigned int*>(sVT);
        const int col = t / 14, i = t - col * 14;
        v32[col * 116 + 100 + i] = 0u;
    }
    if (t < NC) spb[t] = pos_bias[t] * LOG2E;
    if (t < 200) {
        const int row = t >> 2, q = t & 3;
        *reinterpret_cast<bh8*>(sQ + row * 40 + q * 8) =
            *reinterpret_cast<const bh8*>(qh + (size_t)b * (NT * 256) + row * 256 + h * 32 + q * 8);
    }
    for (int u = t; u < 800; u += THREADS) {
        const int row = u >> 2, q = u & 3;
        *reinterpret_cast<bh8*>(sK + row * 40 + q * 8) =
            *reinterpret_cast<const bh8*>(kh + (size_t)b * (NC * 256) + row * 256 + h * 32 + q * 8);
    }
    for (int u = t; u < 800; u += THREADS) {
        const int row = u >> 2, q = u & 3;
        const bh8 vv = *reinterpret_cast<const bh8*>(
            vh + (size_t)b * (NC * 256) + row * 256 + h * 32 + q * 8);
        #pragma unroll
        for (int e = 0; e < 8; ++e)
            sVT[(q * 8 + e) * 232 + row] = (unsigned short)vv[e];
    }
    __syncthreads();

    const int mt = wave & 3, hf = wave >> 2;
    const int m0 = mt << 4;
    const int row64 = m0 + (g << 2);
    int arow = m0 + l15; if (arow > NT - 1) arow = NT - 1;
    const bh8 aq = *reinterpret_cast<const bh8*>(sQ + arow * 40 + (g << 3));

    f4acc acc[7];
    #pragma unroll
    for (int i = 0; i < 7; ++i) {
        const int nt = hf * 7 + i;
        if (nt < 13) {
            const int col = (nt << 4) + l15;
            const int bc = (col < NC) ? col : (NC - 1);
            const bh8 bk = *reinterpret_cast<const bh8*>(sK + bc * 40 + (g << 3));
            f4acc c = {0.f, 0.f, 0.f, 0.f};
            c = mfma_bf16(aq, bk, c);
            const float pbl = spb[bc];
            #pragma unroll
            for (int r = 0; r < 4; ++r)
                acc[i][r] = (col < NC) ? fmaf(c[r], LOG2E, pbl) : -1e30f;
        }
    }
    __syncthreads();

    {
        unsigned int* p32 = reinterpret_cast<unsigned int*>(sP);
        for (int tt = t; tt < 700; tt += THREADS) {
            const int row = tt / 14, i = tt - row * 14;
            p32[row * 116 + 100 + i] = 0u;
        }
    }
    {
        float sl[4] = {0.f, 0.f, 0.f, 0.f};
        #pragma unroll
        for (int i = 0; i < 7; ++i) {
            if (hf * 7 + i < 13) {
                #pragma unroll
                for (int r = 0; r < 4; ++r) {
                    const float e = __builtin_exp2f(acc[i][r]);
                    acc[i][r] = e;
                    sl[r] += e;
                }
            }
        }
        #pragma unroll
        for (int r = 0; r < 4; ++r) {
            sl[r] += __shfl_xor(sl[r], 1);
            sl[r] += __shfl_xor(sl[r], 2);
            sl[r] += __shfl_xor(sl[r], 4);
            sl[r] += __shfl_xor(sl[r], 8);
        }
        if (l15 == 0) {
            #pragma unroll
            for (int r = 0; r < 4; ++r) sSm[hf * 64 + row64 + r] = sl[r];
        }
    }
    __syncthreads();

    {
        float inv[4];
        #pragma unroll
        for (int r = 0; r < 4; ++r)
            inv[r] = 1.0f / (sSm[row64 + r] + sSm[64 + row64 + r]);
        float* attb = att + (size_t)(b * NH + h) * NT * NC;
        #pragma unroll
        for (int i = 0; i < 7; ++i) {
            const int nt = hf * 7 + i;
            if (nt < 13) {
                const int col = (nt << 4) + l15;
                if (col < NC) {
                    #pragma unroll
                    for (int r = 0; r < 4; ++r) {
                        const int row = row64 + r;
                        if (row < NT) {
                            const float v = acc[i][r] * inv[r];
                            attb[row * NC + col] = v;
                            sP[row * 232 + col] = bf16rne(v);
                        }
                    }
                }
            }
        }
    }
    __syncthreads();

    {
        const int pnt = wave >> 2;
        const unsigned short* pA = sP + arow * 232;
        const unsigned short* pB = sVT + (size_t)((pnt << 4) + l15) * 232;
        f4acc o = {0.f, 0.f, 0.f, 0.f};
        #pragma unroll
        for (int ks = 0; ks < 7; ++ks) {
            const bh8 a = *reinterpret_cast<const bh8*>(pA + ks * 32 + (g << 3));
            const bh8 v = *reinterpret_cast<const bh8*>(pB + ks * 32 + (g << 3));
            o = mfma_bf16(a, v, o);
        }
        float* wsb = cat + (size_t)b * (NT * NH * DH) + h * DH;
        #pragma unroll
        for (int r = 0; r < 4; ++r) {
            const int row = row64 + r;
            if (row < NT) wsb[(size_t)row * (NH * DH) + (pnt << 4) + l15] = o[r];
        }
    }
}

// ================= round-8 kernel retained as tier-2/3 fallback =============
template <int WSP>
__global__ __launch_bounds__(THREADS, 4) void attn_mfma(
    const float* __restrict__ gq, const float* __restrict__ gk,
    const float* __restrict__ gv,
    const float* __restrict__ At_w, const float* __restrict__ At_b,
    const float* __restrict__ Ac_w, const float* __restrict__ Ac_b,
    const float* __restrict__ Bc_w, const float* __restrict__ Bc_b,
    const float* __restrict__ pos_bias,
    const float* __restrict__ R_w, const float* __restrict__ R_b,
    float* __restrict__ out, float* __restrict__ att,
    float* __restrict__ cat, const unsigned short* __restrict__ wsp,
    int nbat)
{
    const int t = threadIdx.x;
    const int p = blockIdx.x;
    const int chunk = (nbat * NH) >> 3;
    const int lj = (p & 7) * chunk + (p >> 3);
    const int b = lj >> 3;
    const int h = lj & 7;
    const int lane = t & 63, wave = t >> 6;
    const int l15 = lane & 15, g = lane >> 4;

    __shared__ __align__(16) unsigned char smem[39872];
    unsigned short* sVT = reinterpret_cast<unsigned short*>(smem);
    unsigned short* sK  = reinterpret_cast<unsigned short*>(smem + 14848);
    unsigned short* sQ  = reinterpret_cast<unsigned short*>(smem + 30848);
    unsigned short* sP  = reinterpret_cast<unsigned short*>(smem + 14848);
    float* spb = reinterpret_cast<float*>(smem + 38048);
    float* sSm = reinterpret_cast<float*>(smem + 39360);

    if (t < 448) {
        unsigned int* v32 = reinterpret_cast<unsigned int*>(sVT);
        const int col = t / 14, i = t - col * 14;
        v32[col * 116 + 100 + i] = 0u;
    }
    if (t < NC) spb[t] = pos_bias[t] * LOG2E;

    {
        const int s0 = (wave * 60) >> 3;
        const int s1 = ((wave + 1) * 60) >> 3;
        int cp = -1, cn = -1;
        bh8 wh[4], wl[4];
        float bias = 0.f;
        for (int id = s0; id < s1; ++id) {
            int pidx, nt, mt2;
            if (id < 8)       { pidx = 0; nt = id >> 2; mt2 = id & 3; }
            else if (id < 34) { int jj = id - 8;  pidx = 1; nt = jj / 13; mt2 = jj - nt * 13; }
            else              { int jj = id - 34; pidx = 2; nt = jj / 13; mt2 = jj - nt * 13; }
            const int col = (nt << 4) + l15;
            if (pidx != cp || nt != cn) {
                cp = pidx; cn = nt;
                const int gcol = h * DH + col;
                if (WSP) {
                    const unsigned short* whp =
                        wsp + ((size_t)pidx * 256 + gcol) * 128 + (g << 3);
                    const unsigned short* wlp = whp + WS_PROJ_LO;
                    #pragma unroll
                    for (int ks = 0; ks < 4; ++ks) {
                        wh[ks] = *reinterpret_cast<const bh8*>(whp + ks * 32);
                        wl[ks] = *reinterpret_cast<const bh8*>(wlp + ks * 32);
                    }
                } else {
                    const float* Wm = (pidx == 0) ? At_w : (pidx == 1) ? Ac_w : Bc_w;
                    const float* bp = Wm + (size_t)gcol * EMB + (g << 3);
                    #pragma unroll
                    for (int ks = 0; ks < 4; ++ks) split8(bp + ks * 32, wh[ks], wl[ks]);
                }
                const float* Wb = (pidx == 0) ? At_b : (pidx == 1) ? Ac_b : Bc_b;
                bias = Wb[gcol];
            }
            const int nrows = (pidx == 0) ? NT : NC;
            const float* Xbp = (pidx == 0) ? gq : (pidx == 1) ? gk : gv;
            int ar = mt2 * 16 + l15; if (ar > nrows - 1) ar = nrows - 1;
            const float* ap = Xbp + (size_t)b * nrows * EMB + (size_t)ar * EMB + (g << 3);
            f4acc acc2 = {bias, bias, bias, bias};
            #pragma unroll
            for (int ks = 0; ks < 4; ++ks) {
                bh8 xh, xl;
                split8(ap + ks * 32, xh, xl);
                acc2 = mfma_bf16(xh, wh[ks], acc2);
                acc2 = mfma_bf16(xl, wh[ks], acc2);
                acc2 = mfma_bf16(xh, wl[ks], acc2);
            }
            #pragma unroll
            for (int r = 0; r < 4; ++r) {
                const int row = mt2 * 16 + (g << 2) + r;
                if (row < nrows) {
                    const unsigned short hv = bf16rne(acc2[r]);
                    if (pidx == 0)      sQ[row * 40 + col] = hv;
                    else if (pidx == 1) sK[row * 40 + col] = hv;
                    else                sVT[col * 232 + row] = hv;
                }
            }
        }
    }
    __syncthreads();

    if (t < 250) {
        unsigned short* rowp = (t < 200) ? (sK + t * 40) : (sQ + (t - 200) * 40);
        unsigned int* w32 = reinterpret_cast<unsigned int*>(rowp);
        unsigned int w[16];
        #pragma unroll
        for (int i = 0; i < 16; ++i) w[i] = w32[i];
        float s = 0.f;
        #pragma unroll
        for (int i = 0; i < 16; ++i) {
            const float a = __uint_as_float(w[i] << 16);
            const float c = __uint_as_float(w[i] & 0xFFFF0000u);
            s += a * a + c * c;
        }
        const float rs = rsqrtf(fmaxf(s, 1e-12f));
        #pragma unroll
        for (int i = 0; i < 16; ++i) {
            const float a = __uint_as_float(w[i] << 16) * rs;
            const float c = __uint_as_float(w[i] & 0xFFFF0000u) * rs;
            unsigned int pw;
            asm("v_cvt_pk_bf16_f32 %0, %1, %2" : "=v"(pw) : "v"(a), "v"(c));
            w32[i] = pw;
        }
    }
    __syncthreads();

    const int mt = wave & 3, hf = wave >> 2;
    const int m0 = mt << 4;
    const int row64 = m0 + (g << 2);
    int arow = m0 + l15; if (arow > NT - 1) arow = NT - 1;
    const bh8 aq = *reinterpret_cast<const bh8*>(sQ + arow * 40 + (g << 3));

    f4acc acc[7];
    #pragma unroll
    for (int i = 0; i < 7; ++i) {
        const int nt = hf * 7 + i;
        if (nt < 13) {
            const int col = (nt << 4) + l15;
            const int bc = (col < NC) ? col : (NC - 1);
            const bh8 bk = *reinterpret_cast<const bh8*>(sK + bc * 40 + (g << 3));
            f4acc c = {0.f, 0.f, 0.f, 0.f};
            c = mfma_bf16(aq, bk, c);
            const float pbl = spb[bc];
            #pragma unroll
            for (int r = 0; r < 4; ++r)
                acc[i][r] = (col < NC) ? fmaf(c[r], LOG2E, pbl) : -1e30f;
        }
    }
    __syncthreads();

    {
        unsigned int* p32 = reinterpret_cast<unsigned int*>(sP);
        for (int tt = t; tt < 700; tt += THREADS) {
            const int row = tt / 14, i = tt - row * 14;
            p32[row * 116 + 100 + i] = 0u;
        }
    }
    {
        float sl[4] = {0.f, 0.f, 0.f, 0.f};
        #pragma unroll
        for (int i = 0; i < 7; ++i) {
            if (hf * 7 + i < 13) {
                #pragma unroll
                for (int r = 0; r < 4; ++r) {
                    const float e = __builtin_exp2f(acc[i][r]);
                    acc[i][r] = e;
                    sl[r] += e;
                }
            }
        }
        #pragma unroll
        for (int r = 0; r < 4; ++r) {
            sl[r] += __shfl_xor(sl[r], 1);
            sl[r] += __shfl_xor(sl[r], 2);
            sl[r] += __shfl_xor(sl[r], 4);
            sl[r] += __shfl_xor(sl[r], 8);
        }
        if (l15 == 0) {
            #pragma unroll
            for (int r = 0; r < 4; ++r) sSm[hf * 64 + row64 + r] = sl[r];
        }
    }
    __syncthreads();

    {
        float inv[4];
        #pragma unroll
        for (int r = 0; r < 4; ++r)
            inv[r] = 1.0f / (sSm[row64 + r] + sSm[64 + row64 + r]);
        float* attb = att + (size_t)(b * NH + h) * NT * NC;
        #pragma unroll
        for (int i = 0; i < 7; ++i) {
            const int nt = hf * 7 + i;
            if (nt < 13) {
                const int col = (nt << 4) + l15;
                if (col < NC) {
                    #pragma unroll
                    for (int r = 0; r < 4; ++r) {
                        const int row = row64 + r;
                        if (row < NT) {
                            const float v = acc[i][r] * inv[r];
                            attb[row * NC + col] = v;
                            sP[row * 232 + col] = bf16rne(v);
                        }
                    }
                }
            }
        }
    }
    __syncthreads();

    {
        const int pnt = wave >> 2;
        const unsigned short* pA = sP + arow * 232;
        const unsigned short* pB = sVT + (size_t)((pnt << 4) + l15) * 232;
        f4acc o = {0.f, 0.f, 0.f, 0.f};
        #pragma unroll
        for (int ks = 0; ks < 7; ++ks) {
            const bh8 a = *reinterpret_cast<const bh8*>(pA + ks * 32 + (g << 3));
            const bh8 v = *reinterpret_cast<const bh8*>(pB + ks * 32 + (g << 3));
            o = mfma_bf16(a, v, o);
        }
        if (WSP) {
            float* wsb = cat + (size_t)b * (NT * NH * DH) + h * DH;
            #pragma unroll
            for (int r = 0; r < 4; ++r) {
                const int row = row64 + r;
                if (row < NT) wsb[(size_t)row * (NH * DH) + (pnt << 4) + l15] = o[r];
            }
        } else {
            __syncthreads();
            float* sOH = reinterpret_cast<float*>(smem);
            #pragma unroll
            for (int r = 0; r < 4; ++r) {
                const int row = row64 + r;
                if (row < NT) sOH[row * DH + (pnt << 4) + l15] = o[r];
            }
            __syncthreads();
            for (int oo = t; oo < NT * EMB; oo += THREADS) {
                const int r = oo >> 7, e = oo & 127;
                float s = (h == 0) ? R_b[e] : 0.f;
                const float* rw = R_w + (size_t)e * (NH * DH) + h * DH;
                const float* oh = sOH + r * DH;
                #pragma unroll
                for (int c = 0; c < DH; ++c) s += oh[c] * rw[c];
                atomicAdd(&out[((size_t)b * NT + r) * EMB + e], s);
            }
        }
    }
}

// rproj4: MFMA GEMM. out[51200x128] = cat[51200x256] @ R_w[128x256]^T + R_b.
__global__ __launch_bounds__(256, 4) void rproj4(
    const float* __restrict__ cat, const unsigned short* __restrict__ rhi,
    const float* __restrict__ R_b, float* __restrict__ out)
{
    const int t = threadIdx.x;
    const int lane = t & 63, wave = t >> 6;
    const int l15 = lane & 15, g = lane >> 4;
    const int m0 = blockIdx.x * 64 + wave * 16;
    const float* ap = cat + (size_t)(m0 + l15) * 256 + (g << 3);
    const unsigned short* rlo = rhi + (WS_R_LO - WS_R_HI);

    f4acc acc[8];
    #pragma unroll
    for (int nt = 0; nt < 8; ++nt) {
        const float rb = R_b[nt * 16 + l15];
        acc[nt][0] = rb; acc[nt][1] = rb; acc[nt][2] = rb; acc[nt][3] = rb;
    }
    #pragma unroll
    for (int ks = 0; ks < 8; ++ks) {
        bh8 ah, al;
        split8(ap + ks * 32, ah, al);
        #pragma unroll
        for (int nt = 0; nt < 8; ++nt) {
            const size_t o = (size_t)(nt * 16 + l15) * 256 + ks * 32 + (g << 3);
            const bh8 bh_ = *reinterpret_cast<const bh8*>(rhi + o);
            const bh8 bl_ = *reinterpret_cast<const bh8*>(rlo + o);
            acc[nt] = mfma_bf16(ah, bh_, acc[nt]);
            acc[nt] = mfma_bf16(al, bh_, acc[nt]);
            acc[nt] = mfma_bf16(ah, bl_, acc[nt]);
        }
    }
    const int row = m0 + (g << 2);
    #pragma unroll
    for (int nt = 0; nt < 8; ++nt) {
        #pragma unroll
        for (int r = 0; r < 4; ++r)
            out[(size_t)(row + r) * EMB + nt * 16 + l15] = acc[nt][r];
    }
}

extern "C" void kernel_launch(void* const* d_in, const int* in_sizes, int n_in,
                              void* d_out, int out_size, void* d_ws, size_t ws_size,
                              hipStream_t stream)
{
    const float* gq   = (const float*)d_in[0];
    const float* gk   = (const float*)d_in[1];
    const float* gv   = (const float*)d_in[2];
    const float* At_w = (const float*)d_in[3];
    const float* At_b = (const float*)d_in[4];
    const float* Ac_w = (const float*)d_in[5];
    const float* Ac_b = (const float*)d_in[6];
    const float* Bc_w = (const float*)d_in[7];
    const float* Bc_b = (const float*)d_in[8];
    const float* pb   = (const float*)d_in[9];
    const float* R_w  = (const float*)d_in[10];
    const float* R_b  = (const float*)d_in[11];

    const int nbat = in_sizes[0] / (NT * EMB);   // 1024
    float* out = (float*)d_out;
    float* att = out + (size_t)nbat * NT * EMB;

    const size_t qB   = (size_t)nbat * NT * 256 * 2;
    const size_t kB   = (size_t)nbat * NC * 256 * 2;
    const size_t catB = (size_t)nbat * NT * NH * DH * sizeof(float);
    const size_t need3 = WS_PLANES_B + qB + 2 * kB + catB;   // ~290 MB
    const size_t need2 = WS_PLANES_B + catB;                 // ~53 MB
    const int nwg = nbat * NH;

    if (ws_size >= need3) {
        unsigned short* wsp = (unsigned short*)d_ws;
        unsigned short* qh = (unsigned short*)((char*)d_ws + WS_PLANES_B);
        unsigned short* kh = (unsigned short*)((char*)d_ws + WS_PLANES_B + qB);
        unsigned short* vh = (unsigned short*)((char*)d_ws + WS_PLANES_B + qB + kB);
        float* cat = (float*)((char*)d_ws + WS_PLANES_B + qB + 2 * kB);
        wprep<<<56, 512, 0, stream>>>(At_w, Ac_w, Bc_w, R_w, wsp);
        projn<<<nbat * 3, 512, 0, stream>>>(gq, gk, gv, At_b, Ac_b, Bc_b,
                                            wsp, qh, kh, vh);
        attn2<<<nwg, THREADS, 0, stream>>>(qh, kh, vh, pb, att, cat, nbat);
        rproj4<<<(nbat * NT) / 64, 256, 0, stream>>>(cat, wsp + WS_R_HI, R_b, out);
    } else if (ws_size >= need2) {
        unsigned short* wsp = (unsigned short*)d_ws;
        float* cat = (float*)((char*)d_ws + WS_PLANES_B);
        wprep<<<56, 512, 0, stream>>>(At_w, Ac_w, Bc_w, R_w, wsp);
        attn_mfma<1><<<nwg, THREADS, 0, stream>>>(
            gq, gk, gv, At_w, At_b, Ac_w, Ac_b, Bc_w, Bc_b, pb, R_w, R_b,
            out, att, cat, wsp, nbat);
        rproj4<<<(nbat * NT) / 64, 256, 0, stream>>>(cat, wsp + WS_R_HI, R_b, out);
    } else {
        hipMemsetAsync(d_out, 0, (size_t)nbat * NT * EMB * sizeof(float), stream);
        attn_mfma<0><<<nwg, THREADS, 0, stream>>>(
            gq, gk, gv, At_w, At_b, Ac_w, Ac_b, Bc_w, Bc_b, pb, R_w, R_b,
            out, att, nullptr, nullptr, nbat);
    }
}

// Round 14
// 358.078 us; speedup vs baseline: 1.3285x; 1.3285x over previous
//
#include <hip/hip_runtime.h>

// ---------------------------------------------------------------------------
// Cosine-similarity MHA, round 14:
//  projn v5b: same pipeline as r13 (uniform selects, 2-deep prefetch) but
//    __launch_bounds__(512,4) -> 128-VGPR budget. r13's (512,8) forced a
//    64-VGPR cap -> scratch spill (VGPR=32, FETCH 427MB) -> 257us regression.
//  attn2: back to (512,6) (round-12 proven config).
//  rproj4 / wprep: unchanged.
// ---------------------------------------------------------------------------

#define NT 50
#define NC 200
#define EMB 128
#define DH 32
#define NH 8
#define THREADS 512
#define LOG2E 1.44269504088896340736f

#define WS_PROJ_LO 98304u       // short offset of proj lo plane
#define WS_R_HI    196608u      // short offset of R hi plane
#define WS_R_LO    229376u      // short offset of R lo plane
#define WS_PSW     262144u      // short offset of swizzled proj hi plane
#define WS_PLANES_B 720896u     // bytes: end of weight planes (incl swizzled)

typedef __attribute__((ext_vector_type(4))) float f4acc;
typedef __attribute__((ext_vector_type(8))) short bh8;

__device__ __forceinline__ f4acc mfma_bf16(bh8 a, bh8 b, f4acc c) {
    return __builtin_amdgcn_mfma_f32_16x16x32_bf16(a, b, c, 0, 0, 0);
}

__device__ __forceinline__ unsigned short bf16rne(float x) {
    unsigned int u = __float_as_uint(x);
    u += 0x7FFFu + ((u >> 16) & 1u);
    return (unsigned short)(u >> 16);
}

// 8 f32 -> bf16 RNE (packed); pair order identical for A and B operands.
__device__ __forceinline__ bh8 cvt8(const float* __restrict__ p) {
    float4 x0 = *reinterpret_cast<const float4*>(p);
    float4 x1 = *reinterpret_cast<const float4*>(p + 4);
    float xs[8] = {x0.x, x0.y, x0.z, x0.w, x1.x, x1.y, x1.z, x1.w};
    union { unsigned int w[4]; bh8 v; } H;
    #pragma unroll
    for (int i = 0; i < 4; ++i)
        asm("v_cvt_pk_bf16_f32 %0, %1, %2"
            : "=v"(H.w[i]) : "v"(xs[2 * i]), "v"(xs[2 * i + 1]));
    return H.v;
}

__device__ __forceinline__ void split8(const float* __restrict__ p, bh8& hi, bh8& lo) {
    float4 x0 = *reinterpret_cast<const float4*>(p);
    float4 x1 = *reinterpret_cast<const float4*>(p + 4);
    float xs[8] = {x0.x, x0.y, x0.z, x0.w, x1.x, x1.y, x1.z, x1.w};
    union { unsigned int w[4]; bh8 v; } H, L;
    #pragma unroll
    for (int i = 0; i < 4; ++i) {
        const float a = xs[2 * i], b = xs[2 * i + 1];
        unsigned int hw, lw;
        asm("v_cvt_pk_bf16_f32 %0, %1, %2" : "=v"(hw) : "v"(a), "v"(b));
        const float ha = __uint_as_float(hw << 16);
        const float hb = __uint_as_float(hw & 0xFFFF0000u);
        const float la = a - ha, lb = b - hb;
        asm("v_cvt_pk_bf16_f32 %0, %1, %2" : "=v"(lw) : "v"(la), "v"(lb));
        H.w[i] = hw; L.w[i] = lw;
    }
    hi = H.v; lo = L.v;
}

// ---- wprep: linear hi/lo planes + R planes + fragment-major swizzled plane --
__global__ __launch_bounds__(512) void wprep(
    const float* __restrict__ At_w, const float* __restrict__ Ac_w,
    const float* __restrict__ Bc_w, const float* __restrict__ R_w,
    unsigned short* __restrict__ ws)
{
    const int u = blockIdx.x * 512 + threadIdx.x;     // 28672 units of 8 elems
    bh8 h8, l8;
    if (u < 12288) {                                  // proj: [3][256][128]
        const int p = u >> 12, rem = u & 4095;
        const int col = rem >> 4, e0 = (rem & 15) << 3;
        const float* W = (p == 0) ? At_w : (p == 1) ? Ac_w : Bc_w;
        split8(W + (size_t)col * 128 + e0, h8, l8);
        const size_t o = ((size_t)p * 256 + col) * 128 + e0;
        *reinterpret_cast<bh8*>(ws + o) = h8;
        *reinterpret_cast<bh8*>(ws + WS_PROJ_LO + o) = l8;
    } else if (u < 16384) {                           // R: [128][256]
        const int u2 = u - 12288;
        const int e = u2 >> 5, k0 = (u2 & 31) << 3;
        split8(R_w + (size_t)e * 256 + k0, h8, l8);
        const size_t o = (size_t)e * 256 + k0;
        *reinterpret_cast<bh8*>(ws + WS_R_HI + o) = h8;
        *reinterpret_cast<bh8*>(ws + WS_R_LO + o) = l8;
    } else {                                          // swizzled proj hi
        const int u2 = u - 16384;                     // 12288 units
        const int lane = u2 & 63;
        const int ks = (u2 >> 6) & 3;
        const int colgrp = (u2 >> 8) & 1;
        const int head = (u2 >> 9) & 7;
        const int ty = u2 >> 12;
        const float* W = (ty == 0) ? At_w : (ty == 1) ? Ac_w : Bc_w;
        const int col = head * 32 + colgrp * 16 + (lane & 15);
        const int g = lane >> 4;
        *reinterpret_cast<bh8*>(ws + WS_PSW + (size_t)u2 * 8) =
            cvt8(W + (size_t)col * 128 + ks * 32 + g * 8);
    }
}

__device__ __forceinline__ void projn_wfrag(
    const unsigned short* __restrict__ wsp, int ty, int head, int lane,
    bh8* bf0, bh8* bf1)
{
    const unsigned short* base = wsp + WS_PSW + ((size_t)(ty * 8 + head) << 12)
                               + (size_t)lane * 8;
    #pragma unroll
    for (int ks = 0; ks < 4; ++ks) {
        bf0[ks] = *reinterpret_cast<const bh8*>(base + (ks << 9));
        bf1[ks] = *reinterpret_cast<const bh8*>(base + 2048 + (ks << 9));
    }
}

__device__ __forceinline__ void tinfo(int r, int& ty, int& mt, int& nrows) {
    ty = (r < 4) ? 0 : (r < 17) ? 1 : 2;
    mt = r - ((ty == 0) ? 0 : (ty == 1) ? 4 : 17);
    nrows = (ty == 0) ? NT : NC;
}

// ---- projn v5b: persistent 10-tile pipelined block, 2-deep prefetch ----
// block = (batch, third): tiles r = third*10 .. third*10+9. Wave = head.
// (512,4): 128-VGPR budget -- bf frags (32) + 2-deep prefetch fit unspilled.
__global__ __launch_bounds__(512, 4) void projn(
    const float* __restrict__ gq, const float* __restrict__ gk,
    const float* __restrict__ gv,
    const float* __restrict__ At_b, const float* __restrict__ Ac_b,
    const float* __restrict__ Bc_b,
    const unsigned short* __restrict__ wsp,
    unsigned short* __restrict__ qh, unsigned short* __restrict__ kh,
    unsigned short* __restrict__ vh)
{
    __shared__ __align__(16) float sX[2][16][132];
    __shared__ __align__(16) unsigned short sO[16 * 264];

    const int blk = blockIdx.x;
    const int b = blk / 3, third = blk - b * 3;
    const int t = threadIdx.x;
    const int lane = t & 63, head = t >> 6, l15 = lane & 15, g = lane >> 4;
    const int c0i = head * 32 + l15, c1i = c0i + 16;
    const int srow = t >> 5, scol = (t & 31) * 4;
    const int fr = lane >> 2, fc = lane & 3;

    // uniform base-pointer selects (s_cselect; no arrays -> no scratch)
    #define XBASE(TY) ((TY) == 0 ? gq + (size_t)b * NT * EMB \
                      : (TY) == 1 ? gk + (size_t)b * NC * EMB \
                                  : gv + (size_t)b * NC * EMB)
    #define OBASE(TY) ((TY) == 0 ? qh + (size_t)b * (NT * 256) \
                      : (TY) == 1 ? kh + (size_t)b * (NC * 256) \
                                  : vh + (size_t)b * (NC * 256))
    #define BBASE(TY) ((TY) == 0 ? At_b : (TY) == 1 ? Ac_b : Bc_b)

    const int r0 = third * 10;
    int ty, mt, nrows;
    tinfo(r0, ty, mt, nrows);

    // prologue: stage tile r0 -> sX[0]; W frags + bias for its type
    {
        int row = mt * 16 + srow; if (row > nrows - 1) row = nrows - 1;
        *reinterpret_cast<float4*>(&sX[0][srow][scol]) =
            *reinterpret_cast<const float4*>(XBASE(ty) + (size_t)row * EMB + scol);
    }
    bh8 bf0[4], bf1[4];
    projn_wfrag(wsp, ty, head, lane, bf0, bf1);
    float bias0 = BBASE(ty)[c0i], bias1 = BBASE(ty)[c1i];

    // prefetch tile r0+1 into xregA
    int tyA, mtA, nrA;
    tinfo(r0 + 1, tyA, mtA, nrA);
    float4 xregA;
    {
        int row = mtA * 16 + srow; if (row > nrA - 1) row = nrA - 1;
        xregA = *reinterpret_cast<const float4*>(
            XBASE(tyA) + (size_t)row * EMB + scol);
    }
    __syncthreads();

    for (int i = 0; i < 10; ++i) {
        const int cur = i & 1;
        const int cty = ty, cmt = mt, cnrows = nrows;

        // issue tile i+2 prefetch early (~2 tile-times to complete)
        float4 xregB;
        int tyB = tyA, mtB = mtA, nrB = nrA;
        if (i + 2 < 10) {
            tinfo(r0 + i + 2, tyB, mtB, nrB);
            int row = mtB * 16 + srow; if (row > nrB - 1) row = nrB - 1;
            xregB = *reinterpret_cast<const float4*>(
                XBASE(tyB) + (size_t)row * EMB + scol);
        }

        // compute current tile
        f4acc a0 = {bias0, bias0, bias0, bias0};
        f4acc a1 = {bias1, bias1, bias1, bias1};
        #pragma unroll
        for (int ks = 0; ks < 4; ++ks) {
            const bh8 xv = cvt8(&sX[cur][l15][ks * 32 + (g << 3)]);
            a0 = mfma_bf16(xv, bf0[ks], a0);
            a1 = mfma_bf16(xv, bf1[ks], a1);
        }
        if (cty < 2) {                                 // normalize q/k rows
            float s[4];
            #pragma unroll
            for (int rr = 0; rr < 4; ++rr) s[rr] = a0[rr] * a0[rr] + a1[rr] * a1[rr];
            #pragma unroll
            for (int rr = 0; rr < 4; ++rr) {
                s[rr] += __shfl_xor(s[rr], 1);
                s[rr] += __shfl_xor(s[rr], 2);
                s[rr] += __shfl_xor(s[rr], 4);
                s[rr] += __shfl_xor(s[rr], 8);
            }
            #pragma unroll
            for (int rr = 0; rr < 4; ++rr) {
                const float rs = rsqrtf(fmaxf(s[rr], 1e-12f));
                a0[rr] *= rs; a1[rr] *= rs;
            }
        }
        // pack into sO (wave-private columns head*32..head*32+31)
        #pragma unroll
        for (int rr = 0; rr < 4; ++rr) {
            const int row = (g << 2) + rr;
            sO[row * 264 + c0i] = bf16rne(a0[rr]);
            sO[row * 264 + c1i] = bf16rne(a1[rr]);
        }
        asm volatile("" ::: "memory");                 // pack before flush
        // wave-local flush (same wave wrote these 32 cols; DS in-order)
        {
            const int grow = cmt * 16 + fr;
            if (grow < cnrows)
                *reinterpret_cast<bh8*>(
                    OBASE(cty) + (size_t)grow * 256 + head * 32 + fc * 8) =
                    *reinterpret_cast<const bh8*>(&sO[fr * 264 + head * 32 + fc * 8]);
        }
        // rotate pipeline: write tile i+1 into other sX buffer
        if (i + 1 < 10) {
            *reinterpret_cast<float4*>(&sX[cur ^ 1][srow][scol]) = xregA;
            if (tyA != cty) {
                projn_wfrag(wsp, tyA, head, lane, bf0, bf1);
                bias0 = BBASE(tyA)[c0i]; bias1 = BBASE(tyA)[c1i];
            }
            ty = tyA; mt = mtA; nrows = nrA;
            tyA = tyB; mtA = mtB; nrA = nrB;
            xregA = xregB;
        }
        __syncthreads();
    }
    #undef XBASE
    #undef OBASE
    #undef BBASE
}

// ---- attn2: scores + softmax + att + PV + cat, from prestaged bf16 ----
__global__ __launch_bounds__(512, 6) void attn2(
    const unsigned short* __restrict__ qh, const unsigned short* __restrict__ kh,
    const unsigned short* __restrict__ vh, const float* __restrict__ pos_bias,
    float* __restrict__ att, float* __restrict__ cat, int nbat)
{
    const int t = threadIdx.x;
    const int p = blockIdx.x;
    const int chunk = (nbat * NH) >> 3;
    const int lj = (p & 7) * chunk + (p >> 3);
    const int b = lj >> 3, h = lj & 7;
    const int lane = t & 63, wave = t >> 6, l15 = lane & 15, g = lane >> 4;

    __shared__ __align__(16) unsigned char smem[39872];
    unsigned short* sVT = reinterpret_cast<unsigned short*>(smem);
    unsigned short* sK  = reinterpret_cast<unsigned short*>(smem + 14848);
    unsigned short* sQ  = reinterpret_cast<unsigned short*>(smem + 30848);
    unsigned short* sP  = reinterpret_cast<unsigned short*>(smem + 14848);
    float* spb = reinterpret_cast<float*>(smem + 38048);
    float* sSm = reinterpret_cast<float*>(smem + 39360);

    if (t < 448) {
        unsigned int* v32 = reinterpret_cast<unsigned int*>(sVT);
        const int col = t / 14, i = t - col * 14;
        v32[col * 116 + 100 + i] = 0u;
    }
    if (t < NC) spb[t] = pos_bias[t] * LOG2E;
    if (t < 200) {
        const int row = t >> 2, q = t & 3;
        *reinterpret_cast<bh8*>(sQ + row * 40 + q * 8) =
            *reinterpret_cast<const bh8*>(qh + (size_t)b * (NT * 256) + row * 256 + h * 32 + q * 8);
    }
    for (int u = t; u < 800; u += THREADS) {
        const int row = u >> 2, q = u & 3;
        *reinterpret_cast<bh8*>(sK + row * 40 + q * 8) =
            *reinterpret_cast<const bh8*>(kh + (size_t)b * (NC * 256) + row * 256 + h * 32 + q * 8);
    }
    for (int u = t; u < 800; u += THREADS) {
        const int row = u >> 2, q = u & 3;
        const bh8 vv = *reinterpret_cast<const bh8*>(
            vh + (size_t)b * (NC * 256) + row * 256 + h * 32 + q * 8);
        #pragma unroll
        for (int e = 0; e < 8; ++e)
            sVT[(q * 8 + e) * 232 + row] = (unsigned short)vv[e];
    }
    __syncthreads();

    const int mt = wave & 3, hf = wave >> 2;
    const int m0 = mt << 4;
    const int row64 = m0 + (g << 2);
    int arow = m0 + l15; if (arow > NT - 1) arow = NT - 1;
    const bh8 aq = *reinterpret_cast<const bh8*>(sQ + arow * 40 + (g << 3));

    f4acc acc[7];
    #pragma unroll
    for (int i = 0; i < 7; ++i) {
        const int nt = hf * 7 + i;
        if (nt < 13) {
            const int col = (nt << 4) + l15;
            const int bc = (col < NC) ? col : (NC - 1);
            const bh8 bk = *reinterpret_cast<const bh8*>(sK + bc * 40 + (g << 3));
            f4acc c = {0.f, 0.f, 0.f, 0.f};
            c = mfma_bf16(aq, bk, c);
            const float pbl = spb[bc];
            #pragma unroll
            for (int r = 0; r < 4; ++r)
                acc[i][r] = (col < NC) ? fmaf(c[r], LOG2E, pbl) : -1e30f;
        }
    }
    __syncthreads();

    {
        unsigned int* p32 = reinterpret_cast<unsigned int*>(sP);
        for (int tt = t; tt < 700; tt += THREADS) {
            const int row = tt / 14, i = tt - row * 14;
            p32[row * 116 + 100 + i] = 0u;
        }
    }
    {
        float sl[4] = {0.f, 0.f, 0.f, 0.f};
        #pragma unroll
        for (int i = 0; i < 7; ++i) {
            if (hf * 7 + i < 13) {
                #pragma unroll
                for (int r = 0; r < 4; ++r) {
                    const float e = __builtin_exp2f(acc[i][r]);
                    acc[i][r] = e;
                    sl[r] += e;
                }
            }
        }
        #pragma unroll
        for (int r = 0; r < 4; ++r) {
            sl[r] += __shfl_xor(sl[r], 1);
            sl[r] += __shfl_xor(sl[r], 2);
            sl[r] += __shfl_xor(sl[r], 4);
            sl[r] += __shfl_xor(sl[r], 8);
        }
        if (l15 == 0) {
            #pragma unroll
            for (int r = 0; r < 4; ++r) sSm[hf * 64 + row64 + r] = sl[r];
        }
    }
    __syncthreads();

    {
        float inv[4];
        #pragma unroll
        for (int r = 0; r < 4; ++r)
            inv[r] = 1.0f / (sSm[row64 + r] + sSm[64 + row64 + r]);
        float* attb = att + (size_t)(b * NH + h) * NT * NC;
        #pragma unroll
        for (int i = 0; i < 7; ++i) {
            const int nt = hf * 7 + i;
            if (nt < 13) {
                const int col = (nt << 4) + l15;
                if (col < NC) {
                    #pragma unroll
                    for (int r = 0; r < 4; ++r) {
                        const int row = row64 + r;
                        if (row < NT) {
                            const float v = acc[i][r] * inv[r];
                            attb[row * NC + col] = v;
                            sP[row * 232 + col] = bf16rne(v);
                        }
                    }
                }
            }
        }
    }
    __syncthreads();

    {
        const int pnt = wave >> 2;
        const unsigned short* pA = sP + arow * 232;
        const unsigned short* pB = sVT + (size_t)((pnt << 4) + l15) * 232;
        f4acc o = {0.f, 0.f, 0.f, 0.f};
        #pragma unroll
        for (int ks = 0; ks < 7; ++ks) {
            const bh8 a = *reinterpret_cast<const bh8*>(pA + ks * 32 + (g << 3));
            const bh8 v = *reinterpret_cast<const bh8*>(pB + ks * 32 + (g << 3));
            o = mfma_bf16(a, v, o);
        }
        float* wsb = cat + (size_t)b * (NT * NH * DH) + h * DH;
        #pragma unroll
        for (int r = 0; r < 4; ++r) {
            const int row = row64 + r;
            if (row < NT) wsb[(size_t)row * (NH * DH) + (pnt << 4) + l15] = o[r];
        }
    }
}

// ================= round-8 kernel retained as tier-2/3 fallback =============
template <int WSP>
__global__ __launch_bounds__(THREADS, 4) void attn_mfma(
    const float* __restrict__ gq, const float* __restrict__ gk,
    const float* __restrict__ gv,
    const float* __restrict__ At_w, const float* __restrict__ At_b,
    const float* __restrict__ Ac_w, const float* __restrict__ Ac_b,
    const float* __restrict__ Bc_w, const float* __restrict__ Bc_b,
    const float* __restrict__ pos_bias,
    const float* __restrict__ R_w, const float* __restrict__ R_b,
    float* __restrict__ out, float* __restrict__ att,
    float* __restrict__ cat, const unsigned short* __restrict__ wsp,
    int nbat)
{
    const int t = threadIdx.x;
    const int p = blockIdx.x;
    const int chunk = (nbat * NH) >> 3;
    const int lj = (p & 7) * chunk + (p >> 3);
    const int b = lj >> 3;
    const int h = lj & 7;
    const int lane = t & 63, wave = t >> 6;
    const int l15 = lane & 15, g = lane >> 4;

    __shared__ __align__(16) unsigned char smem[39872];
    unsigned short* sVT = reinterpret_cast<unsigned short*>(smem);
    unsigned short* sK  = reinterpret_cast<unsigned short*>(smem + 14848);
    unsigned short* sQ  = reinterpret_cast<unsigned short*>(smem + 30848);
    unsigned short* sP  = reinterpret_cast<unsigned short*>(smem + 14848);
    float* spb = reinterpret_cast<float*>(smem + 38048);
    float* sSm = reinterpret_cast<float*>(smem + 39360);

    if (t < 448) {
        unsigned int* v32 = reinterpret_cast<unsigned int*>(sVT);
        const int col = t / 14, i = t - col * 14;
        v32[col * 116 + 100 + i] = 0u;
    }
    if (t < NC) spb[t] = pos_bias[t] * LOG2E;

    {
        const int s0 = (wave * 60) >> 3;
        const int s1 = ((wave + 1) * 60) >> 3;
        int cp = -1, cn = -1;
        bh8 wh[4], wl[4];
        float bias = 0.f;
        for (int id = s0; id < s1; ++id) {
            int pidx, nt, mt2;
            if (id < 8)       { pidx = 0; nt = id >> 2; mt2 = id & 3; }
            else if (id < 34) { int jj = id - 8;  pidx = 1; nt = jj / 13; mt2 = jj - nt * 13; }
            else              { int jj = id - 34; pidx = 2; nt = jj / 13; mt2 = jj - nt * 13; }
            const int col = (nt << 4) + l15;
            if (pidx != cp || nt != cn) {
                cp = pidx; cn = nt;
                const int gcol = h * DH + col;
                if (WSP) {
                    const unsigned short* whp =
                        wsp + ((size_t)pidx * 256 + gcol) * 128 + (g << 3);
                    const unsigned short* wlp = whp + WS_PROJ_LO;
                    #pragma unroll
                    for (int ks = 0; ks < 4; ++ks) {
                        wh[ks] = *reinterpret_cast<const bh8*>(whp + ks * 32);
                        wl[ks] = *reinterpret_cast<const bh8*>(wlp + ks * 32);
                    }
                } else {
                    const float* Wm = (pidx == 0) ? At_w : (pidx == 1) ? Ac_w : Bc_w;
                    const float* bp = Wm + (size_t)gcol * EMB + (g << 3);
                    #pragma unroll
                    for (int ks = 0; ks < 4; ++ks) split8(bp + ks * 32, wh[ks], wl[ks]);
                }
                const float* Wb = (pidx == 0) ? At_b : (pidx == 1) ? Ac_b : Bc_b;
                bias = Wb[gcol];
            }
            const int nrows = (pidx == 0) ? NT : NC;
            const float* Xbp = (pidx == 0) ? gq : (pidx == 1) ? gk : gv;
            int ar = mt2 * 16 + l15; if (ar > nrows - 1) ar = nrows - 1;
            const float* ap = Xbp + (size_t)b * nrows * EMB + (size_t)ar * EMB + (g << 3);
            f4acc acc2 = {bias, bias, bias, bias};
            #pragma unroll
            for (int ks = 0; ks < 4; ++ks) {
                bh8 xh, xl;
                split8(ap + ks * 32, xh, xl);
                acc2 = mfma_bf16(xh, wh[ks], acc2);
                acc2 = mfma_bf16(xl, wh[ks], acc2);
                acc2 = mfma_bf16(xh, wl[ks], acc2);
            }
            #pragma unroll
            for (int r = 0; r < 4; ++r) {
                const int row = mt2 * 16 + (g << 2) + r;
                if (row < nrows) {
                    const unsigned short hv = bf16rne(acc2[r]);
                    if (pidx == 0)      sQ[row * 40 + col] = hv;
                    else if (pidx == 1) sK[row * 40 + col] = hv;
                    else                sVT[col * 232 + row] = hv;
                }
            }
        }
    }
    __syncthreads();

    if (t < 250) {
        unsigned short* rowp = (t < 200) ? (sK + t * 40) : (sQ + (t - 200) * 40);
        unsigned int* w32 = reinterpret_cast<unsigned int*>(rowp);
        unsigned int w[16];
        #pragma unroll
        for (int i = 0; i < 16; ++i) w[i] = w32[i];
        float s = 0.f;
        #pragma unroll
        for (int i = 0; i < 16; ++i) {
            const float a = __uint_as_float(w[i] << 16);
            const float c = __uint_as_float(w[i] & 0xFFFF0000u);
            s += a * a + c * c;
        }
        const float rs = rsqrtf(fmaxf(s, 1e-12f));
        #pragma unroll
        for (int i = 0; i < 16; ++i) {
            const float a = __uint_as_float(w[i] << 16) * rs;
            const float c = __uint_as_float(w[i] & 0xFFFF0000u) * rs;
            unsigned int pw;
            asm("v_cvt_pk_bf16_f32 %0, %1, %2" : "=v"(pw) : "v"(a), "v"(c));
            w32[i] = pw;
        }
    }
    __syncthreads();

    const int mt = wave & 3, hf = wave >> 2;
    const int m0 = mt << 4;
    const int row64 = m0 + (g << 2);
    int arow = m0 + l15; if (arow > NT - 1) arow = NT - 1;
    const bh8 aq = *reinterpret_cast<const bh8*>(sQ + arow * 40 + (g << 3));

    f4acc acc[7];
    #pragma unroll
    for (int i = 0; i < 7; ++i) {
        const int nt = hf * 7 + i;
        if (nt < 13) {
            const int col = (nt << 4) + l15;
            const int bc = (col < NC) ? col : (NC - 1);
            const bh8 bk = *reinterpret_cast<const bh8*>(sK + bc * 40 + (g << 3));
            f4acc c = {0.f, 0.f, 0.f, 0.f};
            c = mfma_bf16(aq, bk, c);
            const float pbl = spb[bc];
            #pragma unroll
            for (int r = 0; r < 4; ++r)
                acc[i][r] = (col < NC) ? fmaf(c[r], LOG2E, pbl) : -1e30f;
        }
    }
    __syncthreads();

    {
        unsigned int* p32 = reinterpret_cast<unsigned int*>(sP);
        for (int tt = t; tt < 700; tt += THREADS) {
            const int row = tt / 14, i = tt - row * 14;
            p32[row * 116 + 100 + i] = 0u;
        }
    }
    {
        float sl[4] = {0.f, 0.f, 0.f, 0.f};
        #pragma unroll
        for (int i = 0; i < 7; ++i) {
            if (hf * 7 + i < 13) {
                #pragma unroll
                for (int r = 0; r < 4; ++r) {
                    const float e = __builtin_exp2f(acc[i][r]);
                    acc[i][r] = e;
                    sl[r] += e;
                }
            }
        }
        #pragma unroll
        for (int r = 0; r < 4; ++r) {
            sl[r] += __shfl_xor(sl[r], 1);
            sl[r] += __shfl_xor(sl[r], 2);
            sl[r] += __shfl_xor(sl[r], 4);
            sl[r] += __shfl_xor(sl[r], 8);
        }
        if (l15 == 0) {
            #pragma unroll
            for (int r = 0; r < 4; ++r) sSm[hf * 64 + row64 + r] = sl[r];
        }
    }
    __syncthreads();

    {
        float inv[4];
        #pragma unroll
        for (int r = 0; r < 4; ++r)
            inv[r] = 1.0f / (sSm[row64 + r] + sSm[64 + row64 + r]);
        float* attb = att + (size_t)(b * NH + h) * NT * NC;
        #pragma unroll
        for (int i = 0; i < 7; ++i) {
            const int nt = hf * 7 + i;
            if (nt < 13) {
                const int col = (nt << 4) + l15;
                if (col < NC) {
                    #pragma unroll
                    for (int r = 0; r < 4; ++r) {
                        const int row = row64 + r;
                        if (row < NT) {
                            const float v = acc[i][r] * inv[r];
                            attb[row * NC + col] = v;
                            sP[row * 232 + col] = bf16rne(v);
                        }
                    }
                }
            }
        }
    }
    __syncthreads();

    {
        const int pnt = wave >> 2;
        const unsigned short* pA = sP + arow * 232;
        const unsigned short* pB = sVT + (size_t)((pnt << 4) + l15) * 232;
        f4acc o = {0.f, 0.f, 0.f, 0.f};
        #pragma unroll
        for (int ks = 0; ks < 7; ++ks) {
            const bh8 a = *reinterpret_cast<const bh8*>(pA + ks * 32 + (g << 3));
            const bh8 v = *reinterpret_cast<const bh8*>(pB + ks * 32 + (g << 3));
            o = mfma_bf16(a, v, o);
        }
        if (WSP) {
            float* wsb = cat + (size_t)b * (NT * NH * DH) + h * DH;
            #pragma unroll
            for (int r = 0; r < 4; ++r) {
                const int row = row64 + r;
                if (row < NT) wsb[(size_t)row * (NH * DH) + (pnt << 4) + l15] = o[r];
            }
        } else {
            __syncthreads();
            float* sOH = reinterpret_cast<float*>(smem);
            #pragma unroll
            for (int r = 0; r < 4; ++r) {
                const int row = row64 + r;
                if (row < NT) sOH[row * DH + (pnt << 4) + l15] = o[r];
            }
            __syncthreads();
            for (int oo = t; oo < NT * EMB; oo += THREADS) {
                const int r = oo >> 7, e = oo & 127;
                float s = (h == 0) ? R_b[e] : 0.f;
                const float* rw = R_w + (size_t)e * (NH * DH) + h * DH;
                const float* oh = sOH + r * DH;
                #pragma unroll
                for (int c = 0; c < DH; ++c) s += oh[c] * rw[c];
                atomicAdd(&out[((size_t)b * NT + r) * EMB + e], s);
            }
        }
    }
}

// rproj4: MFMA GEMM. out[51200x128] = cat[51200x256] @ R_w[128x256]^T + R_b.
__global__ __launch_bounds__(256, 4) void rproj4(
    const float* __restrict__ cat, const unsigned short* __restrict__ rhi,
    const float* __restrict__ R_b, float* __restrict__ out)
{
    const int t = threadIdx.x;
    const int lane = t & 63, wave = t >> 6;
    const int l15 = lane & 15, g = lane >> 4;
    const int m0 = blockIdx.x * 64 + wave * 16;
    const float* ap = cat + (size_t)(m0 + l15) * 256 + (g << 3);
    const unsigned short* rlo = rhi + (WS_R_LO - WS_R_HI);

    f4acc acc[8];
    #pragma unroll
    for (int nt = 0; nt < 8; ++nt) {
        const float rb = R_b[nt * 16 + l15];
        acc[nt][0] = rb; acc[nt][1] = rb; acc[nt][2] = rb; acc[nt][3] = rb;
    }
    #pragma unroll
    for (int ks = 0; ks < 8; ++ks) {
        bh8 ah, al;
        split8(ap + ks * 32, ah, al);
        #pragma unroll
        for (int nt = 0; nt < 8; ++nt) {
            const size_t o = (size_t)(nt * 16 + l15) * 256 + ks * 32 + (g << 3);
            const bh8 bh_ = *reinterpret_cast<const bh8*>(rhi + o);
            const bh8 bl_ = *reinterpret_cast<const bh8*>(rlo + o);
            acc[nt] = mfma_bf16(ah, bh_, acc[nt]);
            acc[nt] = mfma_bf16(al, bh_, acc[nt]);
            acc[nt] = mfma_bf16(ah, bl_, acc[nt]);
        }
    }
    const int row = m0 + (g << 2);
    #pragma unroll
    for (int nt = 0; nt < 8; ++nt) {
        #pragma unroll
        for (int r = 0; r < 4; ++r)
            out[(size_t)(row + r) * EMB + nt * 16 + l15] = acc[nt][r];
    }
}

extern "C" void kernel_launch(void* const* d_in, const int* in_sizes, int n_in,
                              void* d_out, int out_size, void* d_ws, size_t ws_size,
                              hipStream_t stream)
{
    const float* gq   = (const float*)d_in[0];
    const float* gk   = (const float*)d_in[1];
    const float* gv   = (const float*)d_in[2];
    const float* At_w = (const float*)d_in[3];
    const float* At_b = (const float*)d_in[4];
    const float* Ac_w = (const float*)d_in[5];
    const float* Ac_b = (const float*)d_in[6];
    const float* Bc_w = (const float*)d_in[7];
    const float* Bc_b = (const float*)d_in[8];
    const float* pb   = (const float*)d_in[9];
    const float* R_w  = (const float*)d_in[10];
    const float* R_b  = (const float*)d_in[11];

    const int nbat = in_sizes[0] / (NT * EMB);   // 1024
    float* out = (float*)d_out;
    float* att = out + (size_t)nbat * NT * EMB;

    const size_t qB   = (size_t)nbat * NT * 256 * 2;
    const size_t kB   = (size_t)nbat * NC * 256 * 2;
    const size_t catB = (size_t)nbat * NT * NH * DH * sizeof(float);
    const size_t need3 = WS_PLANES_B + qB + 2 * kB + catB;   // ~290 MB
    const size_t need2 = WS_PLANES_B + catB;                 // ~53 MB
    const int nwg = nbat * NH;

    if (ws_size >= need3) {
        unsigned short* wsp = (unsigned short*)d_ws;
        unsigned short* qh = (unsigned short*)((char*)d_ws + WS_PLANES_B);
        unsigned short* kh = (unsigned short*)((char*)d_ws + WS_PLANES_B + qB);
        unsigned short* vh = (unsigned short*)((char*)d_ws + WS_PLANES_B + qB + kB);
        float* cat = (float*)((char*)d_ws + WS_PLANES_B + qB + 2 * kB);
        wprep<<<56, 512, 0, stream>>>(At_w, Ac_w, Bc_w, R_w, wsp);
        projn<<<nbat * 3, 512, 0, stream>>>(gq, gk, gv, At_b, Ac_b, Bc_b,
                                            wsp, qh, kh, vh);
        attn2<<<nwg, THREADS, 0, stream>>>(qh, kh, vh, pb, att, cat, nbat);
        rproj4<<<(nbat * NT) / 64, 256, 0, stream>>>(cat, wsp + WS_R_HI, R_b, out);
    } else if (ws_size >= need2) {
        unsigned short* wsp = (unsigned short*)d_ws;
        float* cat = (float*)((char*)d_ws + WS_PLANES_B);
        wprep<<<56, 512, 0, stream>>>(At_w, Ac_w, Bc_w, R_w, wsp);
        attn_mfma<1><<<nwg, THREADS, 0, stream>>>(
            gq, gk, gv, At_w, At_b, Ac_w, Ac_b, Bc_w, Bc_b, pb, R_w, R_b,
            out, att, cat, wsp, nbat);
        rproj4<<<(nbat * NT) / 64, 256, 0, stream>>>(cat, wsp + WS_R_HI, R_b, out);
    } else {
        hipMemsetAsync(d_out, 0, (size_t)nbat * NT * EMB * sizeof(float), stream);
        attn_mfma<0><<<nwg, THREADS, 0, stream>>>(
            gq, gk, gv, At_w, At_b, Ac_w, Ac_b, Bc_w, Bc_b, pb, R_w, R_b,
            out, att, nullptr, nullptr, nbat);
    }
}

// Round 15
// 345.375 us; speedup vs baseline: 1.3774x; 1.0368x over previous
//
#include <hip/hip_runtime.h>

// ---------------------------------------------------------------------------
// Cosine-similarity MHA, round 15:
//  Head-major intermediate layout: qh/kh/vh are [b][h][row][32] (was
//  [b][row][h*32+c]). projn's wave flush becomes 1KB-contiguous stores;
//  attn2's per-head K/V/Q stages become fully linear reads. No other change.
//  projn v5b pipeline, attn2 (512,6), rproj4 / wprep unchanged.
// ---------------------------------------------------------------------------

#define NT 50
#define NC 200
#define EMB 128
#define DH 32
#define NH 8
#define THREADS 512
#define LOG2E 1.44269504088896340736f

#define WS_PROJ_LO 98304u       // short offset of proj lo plane
#define WS_R_HI    196608u      // short offset of R hi plane
#define WS_R_LO    229376u      // short offset of R lo plane
#define WS_PSW     262144u      // short offset of swizzled proj hi plane
#define WS_PLANES_B 720896u     // bytes: end of weight planes (incl swizzled)

typedef __attribute__((ext_vector_type(4))) float f4acc;
typedef __attribute__((ext_vector_type(8))) short bh8;

__device__ __forceinline__ f4acc mfma_bf16(bh8 a, bh8 b, f4acc c) {
    return __builtin_amdgcn_mfma_f32_16x16x32_bf16(a, b, c, 0, 0, 0);
}

__device__ __forceinline__ unsigned short bf16rne(float x) {
    unsigned int u = __float_as_uint(x);
    u += 0x7FFFu + ((u >> 16) & 1u);
    return (unsigned short)(u >> 16);
}

// 8 f32 -> bf16 RNE (packed); pair order identical for A and B operands.
__device__ __forceinline__ bh8 cvt8(const float* __restrict__ p) {
    float4 x0 = *reinterpret_cast<const float4*>(p);
    float4 x1 = *reinterpret_cast<const float4*>(p + 4);
    float xs[8] = {x0.x, x0.y, x0.z, x0.w, x1.x, x1.y, x1.z, x1.w};
    union { unsigned int w[4]; bh8 v; } H;
    #pragma unroll
    for (int i = 0; i < 4; ++i)
        asm("v_cvt_pk_bf16_f32 %0, %1, %2"
            : "=v"(H.w[i]) : "v"(xs[2 * i]), "v"(xs[2 * i + 1]));
    return H.v;
}

__device__ __forceinline__ void split8(const float* __restrict__ p, bh8& hi, bh8& lo) {
    float4 x0 = *reinterpret_cast<const float4*>(p);
    float4 x1 = *reinterpret_cast<const float4*>(p + 4);
    float xs[8] = {x0.x, x0.y, x0.z, x0.w, x1.x, x1.y, x1.z, x1.w};
    union { unsigned int w[4]; bh8 v; } H, L;
    #pragma unroll
    for (int i = 0; i < 4; ++i) {
        const float a = xs[2 * i], b = xs[2 * i + 1];
        unsigned int hw, lw;
        asm("v_cvt_pk_bf16_f32 %0, %1, %2" : "=v"(hw) : "v"(a), "v"(b));
        const float ha = __uint_as_float(hw << 16);
        const float hb = __uint_as_float(hw & 0xFFFF0000u);
        const float la = a - ha, lb = b - hb;
        asm("v_cvt_pk_bf16_f32 %0, %1, %2" : "=v"(lw) : "v"(la), "v"(lb));
        H.w[i] = hw; L.w[i] = lw;
    }
    hi = H.v; lo = L.v;
}

// ---- wprep: linear hi/lo planes + R planes + fragment-major swizzled plane --
__global__ __launch_bounds__(512) void wprep(
    const float* __restrict__ At_w, const float* __restrict__ Ac_w,
    const float* __restrict__ Bc_w, const float* __restrict__ R_w,
    unsigned short* __restrict__ ws)
{
    const int u = blockIdx.x * 512 + threadIdx.x;     // 28672 units of 8 elems
    bh8 h8, l8;
    if (u < 12288) {                                  // proj: [3][256][128]
        const int p = u >> 12, rem = u & 4095;
        const int col = rem >> 4, e0 = (rem & 15) << 3;
        const float* W = (p == 0) ? At_w : (p == 1) ? Ac_w : Bc_w;
        split8(W + (size_t)col * 128 + e0, h8, l8);
        const size_t o = ((size_t)p * 256 + col) * 128 + e0;
        *reinterpret_cast<bh8*>(ws + o) = h8;
        *reinterpret_cast<bh8*>(ws + WS_PROJ_LO + o) = l8;
    } else if (u < 16384) {                           // R: [128][256]
        const int u2 = u - 12288;
        const int e = u2 >> 5, k0 = (u2 & 31) << 3;
        split8(R_w + (size_t)e * 256 + k0, h8, l8);
        const size_t o = (size_t)e * 256 + k0;
        *reinterpret_cast<bh8*>(ws + WS_R_HI + o) = h8;
        *reinterpret_cast<bh8*>(ws + WS_R_LO + o) = l8;
    } else {                                          // swizzled proj hi
        const int u2 = u - 16384;                     // 12288 units
        const int lane = u2 & 63;
        const int ks = (u2 >> 6) & 3;
        const int colgrp = (u2 >> 8) & 1;
        const int head = (u2 >> 9) & 7;
        const int ty = u2 >> 12;
        const float* W = (ty == 0) ? At_w : (ty == 1) ? Ac_w : Bc_w;
        const int col = head * 32 + colgrp * 16 + (lane & 15);
        const int g = lane >> 4;
        *reinterpret_cast<bh8*>(ws + WS_PSW + (size_t)u2 * 8) =
            cvt8(W + (size_t)col * 128 + ks * 32 + g * 8);
    }
}

__device__ __forceinline__ void projn_wfrag(
    const unsigned short* __restrict__ wsp, int ty, int head, int lane,
    bh8* bf0, bh8* bf1)
{
    const unsigned short* base = wsp + WS_PSW + ((size_t)(ty * 8 + head) << 12)
                               + (size_t)lane * 8;
    #pragma unroll
    for (int ks = 0; ks < 4; ++ks) {
        bf0[ks] = *reinterpret_cast<const bh8*>(base + (ks << 9));
        bf1[ks] = *reinterpret_cast<const bh8*>(base + 2048 + (ks << 9));
    }
}

__device__ __forceinline__ void tinfo(int r, int& ty, int& mt, int& nrows) {
    ty = (r < 4) ? 0 : (r < 17) ? 1 : 2;
    mt = r - ((ty == 0) ? 0 : (ty == 1) ? 4 : 17);
    nrows = (ty == 0) ? NT : NC;
}

// ---- projn v5c: persistent 10-tile pipelined block, head-major output ----
// block = (batch, third): tiles r = third*10 .. third*10+9. Wave = head.
// Output layout: [b][h][row][32] shorts -> wave flush is 1KB contiguous.
__global__ __launch_bounds__(512, 4) void projn(
    const float* __restrict__ gq, const float* __restrict__ gk,
    const float* __restrict__ gv,
    const float* __restrict__ At_b, const float* __restrict__ Ac_b,
    const float* __restrict__ Bc_b,
    const unsigned short* __restrict__ wsp,
    unsigned short* __restrict__ qh, unsigned short* __restrict__ kh,
    unsigned short* __restrict__ vh)
{
    __shared__ __align__(16) float sX[2][16][132];
    __shared__ __align__(16) unsigned short sO[16 * 264];

    const int blk = blockIdx.x;
    const int b = blk / 3, third = blk - b * 3;
    const int t = threadIdx.x;
    const int lane = t & 63, head = t >> 6, l15 = lane & 15, g = lane >> 4;
    const int c0i = head * 32 + l15, c1i = c0i + 16;
    const int srow = t >> 5, scol = (t & 31) * 4;
    const int fr = lane >> 2, fc = lane & 3;

    // uniform base-pointer selects (s_cselect; no arrays -> no scratch)
    #define XBASE(TY) ((TY) == 0 ? gq + (size_t)b * NT * EMB \
                      : (TY) == 1 ? gk + (size_t)b * NC * EMB \
                                  : gv + (size_t)b * NC * EMB)
    // head-major: [b][h][nrows][32]
    #define OBASE(TY) ((TY) == 0 ? qh + (size_t)b * (NH * NT * 32) \
                      : (TY) == 1 ? kh + (size_t)b * (NH * NC * 32) \
                                  : vh + (size_t)b * (NH * NC * 32))
    #define BBASE(TY) ((TY) == 0 ? At_b : (TY) == 1 ? Ac_b : Bc_b)

    const int r0 = third * 10;
    int ty, mt, nrows;
    tinfo(r0, ty, mt, nrows);

    // prologue: stage tile r0 -> sX[0]; W frags + bias for its type
    {
        int row = mt * 16 + srow; if (row > nrows - 1) row = nrows - 1;
        *reinterpret_cast<float4*>(&sX[0][srow][scol]) =
            *reinterpret_cast<const float4*>(XBASE(ty) + (size_t)row * EMB + scol);
    }
    bh8 bf0[4], bf1[4];
    projn_wfrag(wsp, ty, head, lane, bf0, bf1);
    float bias0 = BBASE(ty)[c0i], bias1 = BBASE(ty)[c1i];

    // prefetch tile r0+1 into xregA
    int tyA, mtA, nrA;
    tinfo(r0 + 1, tyA, mtA, nrA);
    float4 xregA;
    {
        int row = mtA * 16 + srow; if (row > nrA - 1) row = nrA - 1;
        xregA = *reinterpret_cast<const float4*>(
            XBASE(tyA) + (size_t)row * EMB + scol);
    }
    __syncthreads();

    for (int i = 0; i < 10; ++i) {
        const int cur = i & 1;
        const int cty = ty, cmt = mt, cnrows = nrows;

        // issue tile i+2 prefetch early
        float4 xregB;
        int tyB = tyA, mtB = mtA, nrB = nrA;
        if (i + 2 < 10) {
            tinfo(r0 + i + 2, tyB, mtB, nrB);
            int row = mtB * 16 + srow; if (row > nrB - 1) row = nrB - 1;
            xregB = *reinterpret_cast<const float4*>(
                XBASE(tyB) + (size_t)row * EMB + scol);
        }

        // compute current tile
        f4acc a0 = {bias0, bias0, bias0, bias0};
        f4acc a1 = {bias1, bias1, bias1, bias1};
        #pragma unroll
        for (int ks = 0; ks < 4; ++ks) {
            const bh8 xv = cvt8(&sX[cur][l15][ks * 32 + (g << 3)]);
            a0 = mfma_bf16(xv, bf0[ks], a0);
            a1 = mfma_bf16(xv, bf1[ks], a1);
        }
        if (cty < 2) {                                 // normalize q/k rows
            float s[4];
            #pragma unroll
            for (int rr = 0; rr < 4; ++rr) s[rr] = a0[rr] * a0[rr] + a1[rr] * a1[rr];
            #pragma unroll
            for (int rr = 0; rr < 4; ++rr) {
                s[rr] += __shfl_xor(s[rr], 1);
                s[rr] += __shfl_xor(s[rr], 2);
                s[rr] += __shfl_xor(s[rr], 4);
                s[rr] += __shfl_xor(s[rr], 8);
            }
            #pragma unroll
            for (int rr = 0; rr < 4; ++rr) {
                const float rs = rsqrtf(fmaxf(s[rr], 1e-12f));
                a0[rr] *= rs; a1[rr] *= rs;
            }
        }
        // pack into sO (wave-private columns head*32..head*32+31)
        #pragma unroll
        for (int rr = 0; rr < 4; ++rr) {
            const int row = (g << 2) + rr;
            sO[row * 264 + c0i] = bf16rne(a0[rr]);
            sO[row * 264 + c1i] = bf16rne(a1[rr]);
        }
        asm volatile("" ::: "memory");                 // pack before flush
        // wave-local flush: [b][h][row][32] -> 16 rows x 64B CONTIGUOUS
        {
            const int grow = cmt * 16 + fr;
            if (grow < cnrows)
                *reinterpret_cast<bh8*>(
                    OBASE(cty) + ((size_t)head * cnrows + grow) * 32 + fc * 8) =
                    *reinterpret_cast<const bh8*>(&sO[fr * 264 + head * 32 + fc * 8]);
        }
        // rotate pipeline
        if (i + 1 < 10) {
            *reinterpret_cast<float4*>(&sX[cur ^ 1][srow][scol]) = xregA;
            if (tyA != cty) {
                projn_wfrag(wsp, tyA, head, lane, bf0, bf1);
                bias0 = BBASE(tyA)[c0i]; bias1 = BBASE(tyA)[c1i];
            }
            ty = tyA; mt = mtA; nrows = nrA;
            tyA = tyB; mtA = mtB; nrA = nrB;
            xregA = xregB;
        }
        __syncthreads();
    }
    #undef XBASE
    #undef OBASE
    #undef BBASE
}

// ---- attn2: scores + softmax + att + PV + cat, head-major inputs ----
__global__ __launch_bounds__(512, 6) void attn2(
    const unsigned short* __restrict__ qh, const unsigned short* __restrict__ kh,
    const unsigned short* __restrict__ vh, const float* __restrict__ pos_bias,
    float* __restrict__ att, float* __restrict__ cat, int nbat)
{
    const int t = threadIdx.x;
    const int p = blockIdx.x;
    const int chunk = (nbat * NH) >> 3;
    const int lj = (p & 7) * chunk + (p >> 3);
    const int b = lj >> 3, h = lj & 7;
    const int lane = t & 63, wave = t >> 6, l15 = lane & 15, g = lane >> 4;

    __shared__ __align__(16) unsigned char smem[39872];
    unsigned short* sVT = reinterpret_cast<unsigned short*>(smem);
    unsigned short* sK  = reinterpret_cast<unsigned short*>(smem + 14848);
    unsigned short* sQ  = reinterpret_cast<unsigned short*>(smem + 30848);
    unsigned short* sP  = reinterpret_cast<unsigned short*>(smem + 14848);
    float* spb = reinterpret_cast<float*>(smem + 38048);
    float* sSm = reinterpret_cast<float*>(smem + 39360);

    // head-major slices: contiguous per (b,h)
    const unsigned short* qb = qh + ((size_t)b * NH + h) * (NT * 32);
    const unsigned short* kb = kh + ((size_t)b * NH + h) * (NC * 32);
    const unsigned short* vb = vh + ((size_t)b * NH + h) * (NC * 32);

    if (t < 448) {
        unsigned int* v32 = reinterpret_cast<unsigned int*>(sVT);
        const int col = t / 14, i = t - col * 14;
        v32[col * 116 + 100 + i] = 0u;
    }
    if (t < NC) spb[t] = pos_bias[t] * LOG2E;
    if (t < 200) {                                   // 50 rows x 4 chunks
        const int row = t >> 2, q = t & 3;
        *reinterpret_cast<bh8*>(sQ + row * 40 + q * 8) =
            *reinterpret_cast<const bh8*>(qb + t * 8);       // linear
    }
    for (int u = t; u < 800; u += THREADS) {         // 200 rows x 4 chunks
        const int row = u >> 2, q = u & 3;
        *reinterpret_cast<bh8*>(sK + row * 40 + q * 8) =
            *reinterpret_cast<const bh8*>(kb + u * 8);       // linear
    }
    for (int u = t; u < 800; u += THREADS) {
        const int row = u >> 2, q = u & 3;
        const bh8 vv = *reinterpret_cast<const bh8*>(vb + u * 8);   // linear
        #pragma unroll
        for (int e = 0; e < 8; ++e)
            sVT[(q * 8 + e) * 232 + row] = (unsigned short)vv[e];
    }
    __syncthreads();

    const int mt = wave & 3, hf = wave >> 2;
    const int m0 = mt << 4;
    const int row64 = m0 + (g << 2);
    int arow = m0 + l15; if (arow > NT - 1) arow = NT - 1;
    const bh8 aq = *reinterpret_cast<const bh8*>(sQ + arow * 40 + (g << 3));

    f4acc acc[7];
    #pragma unroll
    for (int i = 0; i < 7; ++i) {
        const int nt = hf * 7 + i;
        if (nt < 13) {
            const int col = (nt << 4) + l15;
            const int bc = (col < NC) ? col : (NC - 1);
            const bh8 bk = *reinterpret_cast<const bh8*>(sK + bc * 40 + (g << 3));
            f4acc c = {0.f, 0.f, 0.f, 0.f};
            c = mfma_bf16(aq, bk, c);
            const float pbl = spb[bc];
            #pragma unroll
            for (int r = 0; r < 4; ++r)
                acc[i][r] = (col < NC) ? fmaf(c[r], LOG2E, pbl) : -1e30f;
        }
    }
    __syncthreads();

    {
        unsigned int* p32 = reinterpret_cast<unsigned int*>(sP);
        for (int tt = t; tt < 700; tt += THREADS) {
            const int row = tt / 14, i = tt - row * 14;
            p32[row * 116 + 100 + i] = 0u;
        }
    }
    {
        float sl[4] = {0.f, 0.f, 0.f, 0.f};
        #pragma unroll
        for (int i = 0; i < 7; ++i) {
            if (hf * 7 + i < 13) {
                #pragma unroll
                for (int r = 0; r < 4; ++r) {
                    const float e = __builtin_exp2f(acc[i][r]);
                    acc[i][r] = e;
                    sl[r] += e;
                }
            }
        }
        #pragma unroll
        for (int r = 0; r < 4; ++r) {
            sl[r] += __shfl_xor(sl[r], 1);
            sl[r] += __shfl_xor(sl[r], 2);
            sl[r] += __shfl_xor(sl[r], 4);
            sl[r] += __shfl_xor(sl[r], 8);
        }
        if (l15 == 0) {
            #pragma unroll
            for (int r = 0; r < 4; ++r) sSm[hf * 64 + row64 + r] = sl[r];
        }
    }
    __syncthreads();

    {
        float inv[4];
        #pragma unroll
        for (int r = 0; r < 4; ++r)
            inv[r] = 1.0f / (sSm[row64 + r] + sSm[64 + row64 + r]);
        float* attb = att + (size_t)(b * NH + h) * NT * NC;
        #pragma unroll
        for (int i = 0; i < 7; ++i) {
            const int nt = hf * 7 + i;
            if (nt < 13) {
                const int col = (nt << 4) + l15;
                if (col < NC) {
                    #pragma unroll
                    for (int r = 0; r < 4; ++r) {
                        const int row = row64 + r;
                        if (row < NT) {
                            const float v = acc[i][r] * inv[r];
                            attb[row * NC + col] = v;
                            sP[row * 232 + col] = bf16rne(v);
                        }
                    }
                }
            }
        }
    }
    __syncthreads();

    {
        const int pnt = wave >> 2;
        const unsigned short* pA = sP + arow * 232;
        const unsigned short* pB = sVT + (size_t)((pnt << 4) + l15) * 232;
        f4acc o = {0.f, 0.f, 0.f, 0.f};
        #pragma unroll
        for (int ks = 0; ks < 7; ++ks) {
            const bh8 a = *reinterpret_cast<const bh8*>(pA + ks * 32 + (g << 3));
            const bh8 v = *reinterpret_cast<const bh8*>(pB + ks * 32 + (g << 3));
            o = mfma_bf16(a, v, o);
        }
        float* wsb = cat + (size_t)b * (NT * NH * DH) + h * DH;
        #pragma unroll
        for (int r = 0; r < 4; ++r) {
            const int row = row64 + r;
            if (row < NT) wsb[(size_t)row * (NH * DH) + (pnt << 4) + l15] = o[r];
        }
    }
}

// ================= round-8 kernel retained as tier-2/3 fallback =============
template <int WSP>
__global__ __launch_bounds__(THREADS, 4) void attn_mfma(
    const float* __restrict__ gq, const float* __restrict__ gk,
    const float* __restrict__ gv,
    const float* __restrict__ At_w, const float* __restrict__ At_b,
    const float* __restrict__ Ac_w, const float* __restrict__ Ac_b,
    const float* __restrict__ Bc_w, const float* __restrict__ Bc_b,
    const float* __restrict__ pos_bias,
    const float* __restrict__ R_w, const float* __restrict__ R_b,
    float* __restrict__ out, float* __restrict__ att,
    float* __restrict__ cat, const unsigned short* __restrict__ wsp,
    int nbat)
{
    const int t = threadIdx.x;
    const int p = blockIdx.x;
    const int chunk = (nbat * NH) >> 3;
    const int lj = (p & 7) * chunk + (p >> 3);
    const int b = lj >> 3;
    const int h = lj & 7;
    const int lane = t & 63, wave = t >> 6;
    const int l15 = lane & 15, g = lane >> 4;

    __shared__ __align__(16) unsigned char smem[39872];
    unsigned short* sVT = reinterpret_cast<unsigned short*>(smem);
    unsigned short* sK  = reinterpret_cast<unsigned short*>(smem + 14848);
    unsigned short* sQ  = reinterpret_cast<unsigned short*>(smem + 30848);
    unsigned short* sP  = reinterpret_cast<unsigned short*>(smem + 14848);
    float* spb = reinterpret_cast<float*>(smem + 38048);
    float* sSm = reinterpret_cast<float*>(smem + 39360);

    if (t < 448) {
        unsigned int* v32 = reinterpret_cast<unsigned int*>(sVT);
        const int col = t / 14, i = t - col * 14;
        v32[col * 116 + 100 + i] = 0u;
    }
    if (t < NC) spb[t] = pos_bias[t] * LOG2E;

    {
        const int s0 = (wave * 60) >> 3;
        const int s1 = ((wave + 1) * 60) >> 3;
        int cp = -1, cn = -1;
        bh8 wh[4], wl[4];
        float bias = 0.f;
        for (int id = s0; id < s1; ++id) {
            int pidx, nt, mt2;
            if (id < 8)       { pidx = 0; nt = id >> 2; mt2 = id & 3; }
            else if (id < 34) { int jj = id - 8;  pidx = 1; nt = jj / 13; mt2 = jj - nt * 13; }
            else              { int jj = id - 34; pidx = 2; nt = jj / 13; mt2 = jj - nt * 13; }
            const int col = (nt << 4) + l15;
            if (pidx != cp || nt != cn) {
                cp = pidx; cn = nt;
                const int gcol = h * DH + col;
                if (WSP) {
                    const unsigned short* whp =
                        wsp + ((size_t)pidx * 256 + gcol) * 128 + (g << 3);
                    const unsigned short* wlp = whp + WS_PROJ_LO;
                    #pragma unroll
                    for (int ks = 0; ks < 4; ++ks) {
                        wh[ks] = *reinterpret_cast<const bh8*>(whp + ks * 32);
                        wl[ks] = *reinterpret_cast<const bh8*>(wlp + ks * 32);
                    }
                } else {
                    const float* Wm = (pidx == 0) ? At_w : (pidx == 1) ? Ac_w : Bc_w;
                    const float* bp = Wm + (size_t)gcol * EMB + (g << 3);
                    #pragma unroll
                    for (int ks = 0; ks < 4; ++ks) split8(bp + ks * 32, wh[ks], wl[ks]);
                }
                const float* Wb = (pidx == 0) ? At_b : (pidx == 1) ? Ac_b : Bc_b;
                bias = Wb[gcol];
            }
            const int nrows = (pidx == 0) ? NT : NC;
            const float* Xbp = (pidx == 0) ? gq : (pidx == 1) ? gk : gv;
            int ar = mt2 * 16 + l15; if (ar > nrows - 1) ar = nrows - 1;
            const float* ap = Xbp + (size_t)b * nrows * EMB + (size_t)ar * EMB + (g << 3);
            f4acc acc2 = {bias, bias, bias, bias};
            #pragma unroll
            for (int ks = 0; ks < 4; ++ks) {
                bh8 xh, xl;
                split8(ap + ks * 32, xh, xl);
                acc2 = mfma_bf16(xh, wh[ks], acc2);
                acc2 = mfma_bf16(xl, wh[ks], acc2);
                acc2 = mfma_bf16(xh, wl[ks], acc2);
            }
            #pragma unroll
            for (int r = 0; r < 4; ++r) {
                const int row = mt2 * 16 + (g << 2) + r;
                if (row < nrows) {
                    const unsigned short hv = bf16rne(acc2[r]);
                    if (pidx == 0)      sQ[row * 40 + col] = hv;
                    else if (pidx == 1) sK[row * 40 + col] = hv;
                    else                sVT[col * 232 + row] = hv;
                }
            }
        }
    }
    __syncthreads();

    if (t < 250) {
        unsigned short* rowp = (t < 200) ? (sK + t * 40) : (sQ + (t - 200) * 40);
        unsigned int* w32 = reinterpret_cast<unsigned int*>(rowp);
        unsigned int w[16];
        #pragma unroll
        for (int i = 0; i < 16; ++i) w[i] = w32[i];
        float s = 0.f;
        #pragma unroll
        for (int i = 0; i < 16; ++i) {
            const float a = __uint_as_float(w[i] << 16);
            const float c = __uint_as_float(w[i] & 0xFFFF0000u);
            s += a * a + c * c;
        }
        const float rs = rsqrtf(fmaxf(s, 1e-12f));
        #pragma unroll
        for (int i = 0; i < 16; ++i) {
            const float a = __uint_as_float(w[i] << 16) * rs;
            const float c = __uint_as_float(w[i] & 0xFFFF0000u) * rs;
            unsigned int pw;
            asm("v_cvt_pk_bf16_f32 %0, %1, %2" : "=v"(pw) : "v"(a), "v"(c));
            w32[i] = pw;
        }
    }
    __syncthreads();

    const int mt = wave & 3, hf = wave >> 2;
    const int m0 = mt << 4;
    const int row64 = m0 + (g << 2);
    int arow = m0 + l15; if (arow > NT - 1) arow = NT - 1;
    const bh8 aq = *reinterpret_cast<const bh8*>(sQ + arow * 40 + (g << 3));

    f4acc acc[7];
    #pragma unroll
    for (int i = 0; i < 7; ++i) {
        const int nt = hf * 7 + i;
        if (nt < 13) {
            const int col = (nt << 4) + l15;
            const int bc = (col < NC) ? col : (NC - 1);
            const bh8 bk = *reinterpret_cast<const bh8*>(sK + bc * 40 + (g << 3));
            f4acc c = {0.f, 0.f, 0.f, 0.f};
            c = mfma_bf16(aq, bk, c);
            const float pbl = spb[bc];
            #pragma unroll
            for (int r = 0; r < 4; ++r)
                acc[i][r] = (col < NC) ? fmaf(c[r], LOG2E, pbl) : -1e30f;
        }
    }
    __syncthreads();

    {
        unsigned int* p32 = reinterpret_cast<unsigned int*>(sP);
        for (int tt = t; tt < 700; tt += THREADS) {
            const int row = tt / 14, i = tt - row * 14;
            p32[row * 116 + 100 + i] = 0u;
        }
    }
    {
        float sl[4] = {0.f, 0.f, 0.f, 0.f};
        #pragma unroll
        for (int i = 0; i < 7; ++i) {
            if (hf * 7 + i < 13) {
                #pragma unroll
                for (int r = 0; r < 4; ++r) {
                    const float e = __builtin_exp2f(acc[i][r]);
                    acc[i][r] = e;
                    sl[r] += e;
                }
            }
        }
        #pragma unroll
        for (int r = 0; r < 4; ++r) {
            sl[r] += __shfl_xor(sl[r], 1);
            sl[r] += __shfl_xor(sl[r], 2);
            sl[r] += __shfl_xor(sl[r], 4);
            sl[r] += __shfl_xor(sl[r], 8);
        }
        if (l15 == 0) {
            #pragma unroll
            for (int r = 0; r < 4; ++r) sSm[hf * 64 + row64 + r] = sl[r];
        }
    }
    __syncthreads();

    {
        float inv[4];
        #pragma unroll
        for (int r = 0; r < 4; ++r)
            inv[r] = 1.0f / (sSm[row64 + r] + sSm[64 + row64 + r]);
        float* attb = att + (size_t)(b * NH + h) * NT * NC;
        #pragma unroll
        for (int i = 0; i < 7; ++i) {
            const int nt = hf * 7 + i;
            if (nt < 13) {
                const int col = (nt << 4) + l15;
                if (col < NC) {
                    #pragma unroll
                    for (int r = 0; r < 4; ++r) {
                        const int row = row64 + r;
                        if (row < NT) {
                            const float v = acc[i][r] * inv[r];
                            attb[row * NC + col] = v;
                            sP[row * 232 + col] = bf16rne(v);
                        }
                    }
                }
            }
        }
    }
    __syncthreads();

    {
        const int pnt = wave >> 2;
        const unsigned short* pA = sP + arow * 232;
        const unsigned short* pB = sVT + (size_t)((pnt << 4) + l15) * 232;
        f4acc o = {0.f, 0.f, 0.f, 0.f};
        #pragma unroll
        for (int ks = 0; ks < 7; ++ks) {
            const bh8 a = *reinterpret_cast<const bh8*>(pA + ks * 32 + (g << 3));
            const bh8 v = *reinterpret_cast<const bh8*>(pB + ks * 32 + (g << 3));
            o = mfma_bf16(a, v, o);
        }
        if (WSP) {
            float* wsb = cat + (size_t)b * (NT * NH * DH) + h * DH;
            #pragma unroll
            for (int r = 0; r < 4; ++r) {
                const int row = row64 + r;
                if (row < NT) wsb[(size_t)row * (NH * DH) + (pnt << 4) + l15] = o[r];
            }
        } else {
            __syncthreads();
            float* sOH = reinterpret_cast<float*>(smem);
            #pragma unroll
            for (int r = 0; r < 4; ++r) {
                const int row = row64 + r;
                if (row < NT) sOH[row * DH + (pnt << 4) + l15] = o[r];
            }
            __syncthreads();
            for (int oo = t; oo < NT * EMB; oo += THREADS) {
                const int r = oo >> 7, e = oo & 127;
                float s = (h == 0) ? R_b[e] : 0.f;
                const float* rw = R_w + (size_t)e * (NH * DH) + h * DH;
                const float* oh = sOH + r * DH;
                #pragma unroll
                for (int c = 0; c < DH; ++c) s += oh[c] * rw[c];
                atomicAdd(&out[((size_t)b * NT + r) * EMB + e], s);
            }
        }
    }
}

// rproj4: MFMA GEMM. out[51200x128] = cat[51200x256] @ R_w[128x256]^T + R_b.
__global__ __launch_bounds__(256, 4) void rproj4(
    const float* __restrict__ cat, const unsigned short* __restrict__ rhi,
    const float* __restrict__ R_b, float* __restrict__ out)
{
    const int t = threadIdx.x;
    const int lane = t & 63, wave = t >> 6;
    const int l15 = lane & 15, g = lane >> 4;
    const int m0 = blockIdx.x * 64 + wave * 16;
    const float* ap = cat + (size_t)(m0 + l15) * 256 + (g << 3);
    const unsigned short* rlo = rhi + (WS_R_LO - WS_R_HI);

    f4acc acc[8];
    #pragma unroll
    for (int nt = 0; nt < 8; ++nt) {
        const float rb = R_b[nt * 16 + l15];
        acc[nt][0] = rb; acc[nt][1] = rb; acc[nt][2] = rb; acc[nt][3] = rb;
    }
    #pragma unroll
    for (int ks = 0; ks < 8; ++ks) {
        bh8 ah, al;
        split8(ap + ks * 32, ah, al);
        #pragma unroll
        for (int nt = 0; nt < 8; ++nt) {
            const size_t o = (size_t)(nt * 16 + l15) * 256 + ks * 32 + (g << 3);
            const bh8 bh_ = *reinterpret_cast<const bh8*>(rhi + o);
            const bh8 bl_ = *reinterpret_cast<const bh8*>(rlo + o);
            acc[nt] = mfma_bf16(ah, bh_, acc[nt]);
            acc[nt] = mfma_bf16(al, bh_, acc[nt]);
            acc[nt] = mfma_bf16(ah, bl_, acc[nt]);
        }
    }
    const int row = m0 + (g << 2);
    #pragma unroll
    for (int nt = 0; nt < 8; ++nt) {
        #pragma unroll
        for (int r = 0; r < 4; ++r)
            out[(size_t)(row + r) * EMB + nt * 16 + l15] = acc[nt][r];
    }
}

extern "C" void kernel_launch(void* const* d_in, const int* in_sizes, int n_in,
                              void* d_out, int out_size, void* d_ws, size_t ws_size,
                              hipStream_t stream)
{
    const float* gq   = (const float*)d_in[0];
    const float* gk   = (const float*)d_in[1];
    const float* gv   = (const float*)d_in[2];
    const float* At_w = (const float*)d_in[3];
    const float* At_b = (const float*)d_in[4];
    const float* Ac_w = (const float*)d_in[5];
    const float* Ac_b = (const float*)d_in[6];
    const float* Bc_w = (const float*)d_in[7];
    const float* Bc_b = (const float*)d_in[8];
    const float* pb   = (const float*)d_in[9];
    const float* R_w  = (const float*)d_in[10];
    const float* R_b  = (const float*)d_in[11];

    const int nbat = in_sizes[0] / (NT * EMB);   // 1024
    float* out = (float*)d_out;
    float* att = out + (size_t)nbat * NT * EMB;

    const size_t qB   = (size_t)nbat * NH * NT * 32 * 2;
    const size_t kB   = (size_t)nbat * NH * NC * 32 * 2;
    const size_t catB = (size_t)nbat * NT * NH * DH * sizeof(float);
    const size_t need3 = WS_PLANES_B + qB + 2 * kB + catB;   // ~290 MB
    const size_t need2 = WS_PLANES_B + catB;                 // ~53 MB
    const int nwg = nbat * NH;

    if (ws_size >= need3) {
        unsigned short* wsp = (unsigned short*)d_ws;
        unsigned short* qh = (unsigned short*)((char*)d_ws + WS_PLANES_B);
        unsigned short* kh = (unsigned short*)((char*)d_ws + WS_PLANES_B + qB);
        unsigned short* vh = (unsigned short*)((char*)d_ws + WS_PLANES_B + qB + kB);
        float* cat = (float*)((char*)d_ws + WS_PLANES_B + qB + 2 * kB);
        wprep<<<56, 512, 0, stream>>>(At_w, Ac_w, Bc_w, R_w, wsp);
        projn<<<nbat * 3, 512, 0, stream>>>(gq, gk, gv, At_b, Ac_b, Bc_b,
                                            wsp, qh, kh, vh);
        attn2<<<nwg, THREADS, 0, stream>>>(qh, kh, vh, pb, att, cat, nbat);
        rproj4<<<(nbat * NT) / 64, 256, 0, stream>>>(cat, wsp + WS_R_HI, R_b, out);
    } else if (ws_size >= need2) {
        unsigned short* wsp = (unsigned short*)d_ws;
        float* cat = (float*)((char*)d_ws + WS_PLANES_B);
        wprep<<<56, 512, 0, stream>>>(At_w, Ac_w, Bc_w, R_w, wsp);
        attn_mfma<1><<<nwg, THREADS, 0, stream>>>(
            gq, gk, gv, At_w, At_b, Ac_w, Ac_b, Bc_w, Bc_b, pb, R_w, R_b,
            out, att, cat, wsp, nbat);
        rproj4<<<(nbat * NT) / 64, 256, 0, stream>>>(cat, wsp + WS_R_HI, R_b, out);
    } else {
        hipMemsetAsync(d_out, 0, (size_t)nbat * NT * EMB * sizeof(float), stream);
        attn_mfma<0><<<nwg, THREADS, 0, stream>>>(
            gq, gk, gv, At_w, At_b, Ac_w, Ac_b, Bc_w, Bc_b, pb, R_w, R_b,
            out, att, nullptr, nullptr, nbat);
    }
}